// Round 17
// baseline (125.289 us; speedup 1.0000x reference)
//
#include <hip/hip_runtime.h>
#include <hip/hip_bf16.h>

#define S 4096
#define D 1024
#define NH 16
#define HD 64

typedef float f32x4 __attribute__((ext_vector_type(4)));
typedef float f32x16 __attribute__((ext_vector_type(16)));
typedef __bf16 bf16x8 __attribute__((ext_vector_type(8)));

#define MFMA16(a, b, c) __builtin_amdgcn_mfma_f32_16x16x32_bf16((a), (b), (c), 0, 0, 0)
#define MFMA32(a, b, c) __builtin_amdgcn_mfma_f32_32x32x16_bf16((a), (b), (c), 0, 0, 0)

__device__ __forceinline__ unsigned short f2bf(float f) {
  unsigned int u = __builtin_bit_cast(unsigned int, f);
  u += 0x7FFFu + ((u >> 16) & 1u);
  return (unsigned short)(u >> 16);
}

__device__ __forceinline__ float bf2f(unsigned short u) {
  unsigned int x = ((unsigned int)u) << 16;
  return __builtin_bit_cast(float, x);
}

__device__ __forceinline__ unsigned cvtpk(float lo, float hi) {
  unsigned r;
  asm("v_cvt_pk_bf16_f32 %0, %1, %2" : "=v"(r) : "v"(lo), "v"(hi));
  return r;
}

// exchange: a.hi-lanes <-> b.lo-lanes (a'[i>=32]=b[i-32], b'[i<32]=a[i+32])
__device__ __forceinline__ void pl32swap(unsigned& a, unsigned& b) {
#if __has_builtin(__builtin_amdgcn_permlane32_swap)
  typedef unsigned u32x2 __attribute__((ext_vector_type(2)));
  u32x2 r = __builtin_amdgcn_permlane32_swap(a, b, false, false);
  a = r.x;
  b = r.y;
#else
  asm volatile("v_permlane32_swap_b32 %0, %1" : "+v"(a), "+v"(b));
#endif
}

typedef __attribute__((address_space(1))) void GAS;
typedef __attribute__((address_space(3))) void LAS;

__device__ __forceinline__ void gld_lds16(const unsigned short* g, unsigned short* l) {
  __builtin_amdgcn_global_load_lds((GAS*)g, (LAS*)l, 16, 0, 0);
}

// ---------------------------------------------------------------------------
// fused f32 -> bf16 convert of hidden (1048576 f4), qkv_w (786432 f4),
// proj_w (262144 f4) in one launch. 8192 blocks x 256 threads.
// ---------------------------------------------------------------------------
__global__ void cvt3(const float* __restrict__ a, unsigned short* __restrict__ ao,
                     const float* __restrict__ b, unsigned short* __restrict__ bo,
                     const float* __restrict__ c, unsigned short* __restrict__ co) {
  int i = blockIdx.x * blockDim.x + threadIdx.x;
  const float* in;
  unsigned short* out;
  int j;
  if (i < 1048576) { in = a; out = ao; j = i; }
  else if (i < 1835008) { in = b; out = bo; j = i - 1048576; }
  else { in = c; out = co; j = i - 1835008; }
  float4 v = ((const float4*)in)[j];
  ushort4 u;
  u.x = f2bf(v.x); u.y = f2bf(v.y); u.z = f2bf(v.z); u.w = f2bf(v.w);
  ((ushort4*)out)[j] = u;
}

// bijective XCD swizzle of a linear block id (nwg % 8 == 0)
__device__ __forceinline__ int xcd_swz(int bid, int nwg) {
  int q = nwg >> 3;
  return (bid & 7) * q + (bid >> 3);
}

// --- Deep-pipelined K-step macros (K=1024, BK=32, 3 static buffer pairs) ----
#define DSTEP_S(RA, RB, SA, SB, KN, VM)                                          \
  {                                                                              \
    bf16x8 af[4], bfv[4];                                                        \
    _Pragma("unroll") for (int mf = 0; mf < 4; ++mf)                             \
        af[mf] = *(const bf16x8*)&RA[(wr * 64 + mf * 16 + l15) * 32 + l4 * 8];   \
    _Pragma("unroll") for (int nf = 0; nf < 4; ++nf)                             \
        bfv[nf] = *(const bf16x8*)&RB[(wc * 64 + nf * 16 + l15) * 32 + l4 * 8];  \
    gld_lds16(Ab + (size_t)r0 * 1024 + (KN) + o0, &SA[w * 512]);                 \
    gld_lds16(Ab + (size_t)r1 * 1024 + (KN) + o1, &SA[2048 + w * 512]);          \
    gld_lds16(Bb + (size_t)r0 * 1024 + (KN) + o0, &SB[w * 512]);                 \
    gld_lds16(Bb + (size_t)r1 * 1024 + (KN) + o1, &SB[2048 + w * 512]);          \
    __builtin_amdgcn_s_setprio(1);                                               \
    _Pragma("unroll") for (int mf = 0; mf < 4; ++mf)                             \
        _Pragma("unroll") for (int nf = 0; nf < 4; ++nf)                         \
            acc[mf][nf] = MFMA16(af[mf], bfv[nf], acc[mf][nf]);                  \
    __builtin_amdgcn_s_setprio(0);                                               \
    asm volatile("s_waitcnt vmcnt(" VM ")" ::: "memory");                        \
    __builtin_amdgcn_s_barrier();                                                \
  }

#define DSTEP_N(RA, RB, VM)                                                      \
  {                                                                              \
    bf16x8 af[4], bfv[4];                                                        \
    _Pragma("unroll") for (int mf = 0; mf < 4; ++mf)                             \
        af[mf] = *(const bf16x8*)&RA[(wr * 64 + mf * 16 + l15) * 32 + l4 * 8];   \
    _Pragma("unroll") for (int nf = 0; nf < 4; ++nf)                             \
        bfv[nf] = *(const bf16x8*)&RB[(wc * 64 + nf * 16 + l15) * 32 + l4 * 8];  \
    __builtin_amdgcn_s_setprio(1);                                               \
    _Pragma("unroll") for (int mf = 0; mf < 4; ++mf)                             \
        _Pragma("unroll") for (int nf = 0; nf < 4; ++nf)                         \
            acc[mf][nf] = MFMA16(af[mf], bfv[nf], acc[mf][nf]);                  \
    __builtin_amdgcn_s_setprio(0);                                               \
    asm volatile("s_waitcnt vmcnt(" VM ")" ::: "memory");                        \
    __builtin_amdgcn_s_barrier();                                                \
  }

#define DSTEP_LAST(RA, RB)                                                       \
  {                                                                              \
    bf16x8 af[4], bfv[4];                                                        \
    _Pragma("unroll") for (int mf = 0; mf < 4; ++mf)                             \
        af[mf] = *(const bf16x8*)&RA[(wr * 64 + mf * 16 + l15) * 32 + l4 * 8];   \
    _Pragma("unroll") for (int nf = 0; nf < 4; ++nf)                             \
        bfv[nf] = *(const bf16x8*)&RB[(wc * 64 + nf * 16 + l15) * 32 + l4 * 8];  \
    __builtin_amdgcn_s_setprio(1);                                               \
    _Pragma("unroll") for (int mf = 0; mf < 4; ++mf)                             \
        _Pragma("unroll") for (int nf = 0; nf < 4; ++nf)                         \
            acc[mf][nf] = MFMA16(af[mf], bfv[nf], acc[mf][nf]);                  \
    __builtin_amdgcn_s_setprio(0);                                               \
  }

#define GEMM_PRO_LOOP()                                                          \
  gld_lds16(Ab + (size_t)r0 * 1024 + o0, &As0[w * 512]);                         \
  gld_lds16(Ab + (size_t)r1 * 1024 + o1, &As0[2048 + w * 512]);                  \
  gld_lds16(Bb + (size_t)r0 * 1024 + o0, &Bs0[w * 512]);                         \
  gld_lds16(Bb + (size_t)r1 * 1024 + o1, &Bs0[2048 + w * 512]);                  \
  gld_lds16(Ab + (size_t)r0 * 1024 + 32 + o0, &As1[w * 512]);                    \
  gld_lds16(Ab + (size_t)r1 * 1024 + 32 + o1, &As1[2048 + w * 512]);             \
  gld_lds16(Bb + (size_t)r0 * 1024 + 32 + o0, &Bs1[w * 512]);                    \
  gld_lds16(Bb + (size_t)r1 * 1024 + 32 + o1, &Bs1[2048 + w * 512]);             \
  asm volatile("s_waitcnt vmcnt(4)" ::: "memory");                               \
  __builtin_amdgcn_s_barrier();                                                  \
  _Pragma("unroll 1") for (int k0 = 0; k0 < 960; k0 += 96) {                     \
    DSTEP_S(As0, Bs0, As2, Bs2, k0 + 64, "4")                                    \
    DSTEP_S(As1, Bs1, As0, Bs0, k0 + 96, "4")                                    \
    DSTEP_S(As2, Bs2, As1, Bs1, k0 + 128, "4")                                   \
  }                                                                              \
  DSTEP_N(As0, Bs0, "0")                                                         \
  DSTEP_LAST(As1, Bs1)

// ---------------------------------------------------------------------------
// QKV GEMM: qkv[4096 x 3072] = hidden @ qkv_w^T + b. L2-partitioned per XCD.
// 3-deep counted-vmcnt pipelined K-loop, launch_bounds(256,3) -> 3 blocks/CU.
// ---------------------------------------------------------------------------
__global__ __launch_bounds__(256, 3) void gemm_qkv(const unsigned short* __restrict__ A,
                                                   const unsigned short* __restrict__ B,
                                                   const float* __restrict__ bias,
                                                   unsigned short* __restrict__ qk,
                                                   unsigned short* __restrict__ vt) {
  __shared__ __align__(16) unsigned short As0[4096], As1[4096], As2[4096];
  __shared__ __align__(16) unsigned short Bs0[4096], Bs1[4096], Bs2[4096];
  __shared__ __align__(16) unsigned short tr[128 * 17];  // 16-col transpose chunk
  const int t = threadIdx.x;
  const int lane = t & 63;
  const int w = t >> 6;
  const int wr = w >> 1, wc = w & 1;
  const int l15 = lane & 15, l4 = lane >> 4;
  const int bid = blockIdx.y * 24 + blockIdx.x;
  const int r8 = bid & 7, i = bid >> 3;
  const int by = (r8 >> 1) * 8 + i / 12;
  const int bx = (r8 & 1) * 12 + i % 12;
  const int m0 = by * 128, n0 = bx * 128;

  f32x4 acc[4][4] = {};

  const int r0 = t >> 2, o0 = (t & 3) * 8;
  const int r1 = (256 + t) >> 2, o1 = ((256 + t) & 3) * 8;
  const unsigned short* Ab = A + (size_t)m0 * 1024;
  const unsigned short* Bb = B + (size_t)n0 * 1024;

  GEMM_PRO_LOOP()

  if (n0 < 2048) {
#pragma unroll
    for (int mf = 0; mf < 4; ++mf)
#pragma unroll
      for (int nf = 0; nf < 4; ++nf) {
        int rr = m0 + wr * 64 + mf * 16 + l4 * 4;
        int cc = n0 + wc * 64 + nf * 16 + l15;
        float bv = bias[cc];
#pragma unroll
        for (int j = 0; j < 4; ++j)
          qk[(size_t)(rr + j) * 2048 + cc] = f2bf(acc[mf][nf][j] + bv);
      }
  } else {
    const int h0 = (n0 - 2048) >> 6;
#pragma unroll
    for (int ch = 0; ch < 8; ++ch) {
      __syncthreads();
      if (wc == (ch >> 2)) {
        const int nf = ch & 3;
        const float bv = bias[n0 + (ch >> 2) * 64 + nf * 16 + l15];
#pragma unroll
        for (int mf = 0; mf < 4; ++mf) {
          int srow = wr * 64 + mf * 16 + l4 * 4;
#pragma unroll
          for (int j = 0; j < 4; ++j)
            tr[(srow + j) * 17 + l15] = f2bf(acc[mf][nf][j] + bv);
        }
      }
      __syncthreads();
      const int hh = h0 + (ch >> 2);
      const int dbase = (ch & 3) * 16;
#pragma unroll
      for (int i2 = 0; i2 < 2; ++i2) {
        int g = i2 * 256 + t;
        int dp = g >> 5, sg = g & 31;
        ushort4 u;
        u.x = tr[(sg * 4 + 0) * 17 + dp];
        u.y = tr[(sg * 4 + 1) * 17 + dp];
        u.z = tr[(sg * 4 + 2) * 17 + dp];
        u.w = tr[(sg * 4 + 3) * 17 + dp];
        *(ushort4*)(vt + (size_t)hh * HD * S + (size_t)(dbase + dp) * S + m0 + sg * 4) = u;
      }
    }
  }
}

// ---------------------------------------------------------------------------
// proj GEMM: out f32 = A bf16 @ B^T bf16 + bias. Same pipelined K-loop.
// ---------------------------------------------------------------------------
__global__ __launch_bounds__(256, 3) void gemm_bt(const unsigned short* __restrict__ A,
                                                  const unsigned short* __restrict__ B,
                                                  const float* __restrict__ bias,
                                                  float* __restrict__ C,
                                                  int M, int N, int K, int gx) {
  __shared__ __align__(16) unsigned short As0[4096], As1[4096], As2[4096];
  __shared__ __align__(16) unsigned short Bs0[4096], Bs1[4096], Bs2[4096];
  const int t = threadIdx.x;
  const int lane = t & 63;
  const int w = t >> 6;
  const int wr = w >> 1, wc = w & 1;
  const int l15 = lane & 15, l4 = lane >> 4;
  const int nwg = gridDim.x * gridDim.y;
  const int nbid = xcd_swz(blockIdx.y * gx + blockIdx.x, nwg);
  const int m0 = (nbid / gx) * 128, n0 = (nbid % gx) * 128;

  f32x4 acc[4][4] = {};

  const int r0 = t >> 2, o0 = (t & 3) * 8;
  const int r1 = (256 + t) >> 2, o1 = ((256 + t) & 3) * 8;
  const unsigned short* Ab = A + (size_t)m0 * 1024;
  const unsigned short* Bb = B + (size_t)n0 * 1024;

  GEMM_PRO_LOOP()

#pragma unroll
  for (int mf = 0; mf < 4; ++mf) {
#pragma unroll
    for (int nf = 0; nf < 4; ++nf) {
      int rr = m0 + wr * 64 + mf * 16 + l4 * 4;
      int cc = n0 + wc * 64 + nf * 16 + l15;
      float bv = bias[cc];
#pragma unroll
      for (int j = 0; j < 4; ++j)
        C[(size_t)(rr + j) * N + cc] = acc[mf][nf][j] + bv;
    }
  }
}

// ---------------------------------------------------------------------------
// Per-row RMSNorm + RoPE from bf16 qk rows -> head-major q/k [NH][S][HD].
// q scaled by 0.125*log2(e). Trig of the 32 unique freqs computed once into
// LDS by lanes 0-63 (was 2048 redundant cosf/sinf per block).
// ---------------------------------------------------------------------------
__global__ __launch_bounds__(256) void norm_rope(const unsigned short* __restrict__ qk,
                                                 const float* __restrict__ qw,
                                                 const float* __restrict__ kw,
                                                 const float* __restrict__ fr,
                                                 unsigned short* __restrict__ qo,
                                                 unsigned short* __restrict__ ko) {
  __shared__ float buf[1024];
  __shared__ float red[4];
  __shared__ float scs[32], ssn[32];
  const int s = blockIdx.x, t = threadIdx.x;
  const int lane = t & 63, w = t >> 6;
  const int e = t * 4;
  const int hh = e >> 6, dd = e & 63;
  const float* frow = fr + (size_t)s * 32;
  if (t < 32) {
    float f = frow[t];
    scs[t] = cosf(f);
    ssn[t] = sinf(f);
  }
  __syncthreads();
  float cs[4], sn[4];
#pragma unroll
  for (int i = 0; i < 4; ++i) {
    int fi = (dd + i) & 31;
    cs[i] = scs[fi];
    sn[i] = ssn[fi];
  }
  for (int part = 0; part < 2; ++part) {
    const unsigned short* row = qk + (size_t)s * 2048 + part * 1024;
    const float* wvp = part ? kw : qw;
    unsigned short* op = part ? ko : qo;
    const float oscale = part ? 1.0f : 0.18033688011112042f;
    ushort4 uv = *(const ushort4*)(row + e);
    float vx = bf2f(uv.x), vy = bf2f(uv.y), vz = bf2f(uv.z), vw = bf2f(uv.w);
    float ssq = vx * vx + vy * vy + vz * vz + vw * vw;
#pragma unroll
    for (int off = 1; off < 64; off <<= 1) ssq += __shfl_xor(ssq, off, 64);
    if (part) __syncthreads();
    if (lane == 0) red[w] = ssq;
    __syncthreads();
    float inv = rsqrtf((red[0] + red[1] + red[2] + red[3]) * (1.0f / 1024.0f) + 1e-6f);
    float4 wv = *(const float4*)(wvp + e);
    buf[e + 0] = vx * inv * wv.x;
    buf[e + 1] = vy * inv * wv.y;
    buf[e + 2] = vz * inv * wv.z;
    buf[e + 3] = vw * inv * wv.w;
    __syncthreads();
    unsigned short ov[4];
#pragma unroll
    for (int i = 0; i < 4; ++i) {
      int di = dd + i;
      float x = buf[e + i];
      float rot = (di < 32) ? -buf[e + i + 32] : buf[e + i - 32];
      ov[i] = f2bf((x * cs[i] + rot * sn[i]) * oscale);
    }
    unsigned short* dst = op + (size_t)hh * S * HD + (size_t)s * HD + dd;
    dst[0] = ov[0]; dst[1] = ov[1]; dst[2] = ov[2]; dst[3] = ov[3];
  }
}

// ---------------------------------------------------------------------------
// QK^T (32x32): S^T[kv 64][q 32] += K . Q^T from swizzled [64][64] K LDS tile.
// ---------------------------------------------------------------------------
__device__ __forceinline__ void qk_tile32(f32x16& s0, f32x16& s1,
                                          const unsigned short* Kbuf,
                                          const bf16x8* qB, int l31, int l5) {
  const int x7 = l31 & 7;
#pragma unroll
  for (int c = 0; c < 4; ++c) {
    const int ch = (2 * c + l5) ^ x7;
    bf16x8 ka0 = *(const bf16x8*)&Kbuf[l31 * 64 + ch * 8];
    bf16x8 ka1 = *(const bf16x8*)&Kbuf[(32 + l31) * 64 + ch * 8];
    s0 = MFMA32(ka0, qB[c], s0);
    s1 = MFMA32(ka1, qB[c], s1);
  }
}

// ---------------------------------------------------------------------------
// Flash attention over a 512-wide kv HALF (kv-split for occupancy: grid 1024
// = 4 blocks/CU, was 512 = 2). Writes RAW partial O (f32) + per-row (l,m);
// attn_combine merges. Structure otherwise = round-14 (32x32 MFMA, swapped
// QK^T, defer-max, cvt_pk+permlane, 2-deep pipeline, K dbuf + V 3-ring).
// ---------------------------------------------------------------------------
__global__ __launch_bounds__(256) void attn_kernel(const unsigned short* __restrict__ q,
                                                   const unsigned short* __restrict__ k,
                                                   const unsigned short* __restrict__ vt,
                                                   float* __restrict__ O1,
                                                   float* __restrict__ O2,
                                                   float2* __restrict__ lmb) {
  __shared__ __align__(16) unsigned short Ks[2][4096];
  __shared__ __align__(16) unsigned short Vs[3][4096];
  const int bid = blockIdx.x;
  const int xcd = bid & 7;
  const int idx = bid >> 3;        // 0..127
  const int half = idx & 1;
  const int qt = (idx >> 1) & 7;
  const int gw = idx >> 4;         // 0..7
  const int g = xcd * 8 + gw;
  const int h = g >> 2, seg = g & 3;
  const int t = threadIdx.x, lane = t & 63, w = t >> 6;
  const int l31 = lane & 31, l5 = lane >> 5;
  const size_t hb = (size_t)h * S * HD;
  const int q0 = seg * 1024 + qt * 128 + w * 32;
  const int kvbase = seg * 1024 + half * 512;

  const int sr = t >> 3;               // tile row 0..31
  const int scb = (t & 7) ^ (sr & 7);  // swizzled source column-chunk
  const unsigned short* ksrcA = k + hb + (size_t)(kvbase + sr) * HD + scb * 8;
  const unsigned short* ksrcB = ksrcA + 32 * HD;
  const unsigned short* vsrcA = vt + (size_t)h * HD * S + (size_t)sr * S + kvbase + scb * 8;
  const unsigned short* vsrcB = vsrcA + (size_t)32 * S;

  // Q B-frags: 4 d-chunks of 16
  const unsigned short* qp = q + hb + (size_t)(q0 + l31) * HD + l5 * 8;
  bf16x8 qB[4];
#pragma unroll
  for (int c = 0; c < 4; ++c) qB[c] = *(const bf16x8*)(qp + 16 * c);

  f32x16 o0 = {}, o1 = {};
  float m = -1e30f, l = 0.f;

  // prologue: stage K0,K1,V0,V1 (of this half)
  gld_lds16(ksrcA, &Ks[0][w * 512]);
  gld_lds16(ksrcB, &Ks[0][2048 + w * 512]);
  gld_lds16(ksrcA + 4096, &Ks[1][w * 512]);
  gld_lds16(ksrcB + 4096, &Ks[1][2048 + w * 512]);
  gld_lds16(vsrcA, &Vs[0][w * 512]);
  gld_lds16(vsrcB, &Vs[0][2048 + w * 512]);
  gld_lds16(vsrcA + 64, &Vs[1][w * 512]);
  gld_lds16(vsrcB + 64, &Vs[1][2048 + w * 512]);
  __syncthreads();

  f32x16 cur0 = {}, cur1 = {};
  qk_tile32(cur0, cur1, Ks[0], qB, l31, l5);
  __syncthreads();  // tile-0 K reads retired before iter0 overwrites Ks[0]

#pragma unroll
  for (int it = 0; it < 8; ++it) {
    // stage tile it+2
    if (it < 6) {
      gld_lds16(ksrcA + (it + 2) * 4096, &Ks[it & 1][w * 512]);
      gld_lds16(ksrcB + (it + 2) * 4096, &Ks[it & 1][2048 + w * 512]);
      gld_lds16(vsrcA + (it + 2) * 64, &Vs[(it + 2) % 3][w * 512]);
      gld_lds16(vsrcB + (it + 2) * 64, &Vs[(it + 2) % 3][2048 + w * 512]);
    }
    // issue QK MFMAs for tile it+1 (consumed next iteration)
    f32x16 nxt0 = {}, nxt1 = {};
    if (it < 7) {
      __builtin_amdgcn_s_setprio(1);
      qk_tile32(nxt0, nxt1, Ks[(it + 1) & 1], qB, l31, l5);
      __builtin_amdgcn_s_setprio(0);
      __builtin_amdgcn_sched_barrier(0);
    }
    // ---- in-register softmax on cur (32 values/lane), exp2, defer-max ----
    float mm[16];
#pragma unroll
    for (int i = 0; i < 16; ++i) mm[i] = fmaxf(cur0[i], cur1[i]);
#pragma unroll
    for (int st = 8; st > 0; st >>= 1)
#pragma unroll
      for (int i = 0; i < 8; ++i)
        if (i < st) mm[i] = fmaxf(mm[i], mm[i + st]);
    float lmax = fmaxf(mm[0], __shfl_xor(mm[0], 32, 64));
    if (!__all(lmax <= m + 8.0f)) {  // rescale (always on it==0)
      const float mn = fmaxf(m, lmax);
      const float corr = exp2f(m - mn);
      m = mn;
      l *= corr;
#pragma unroll
      for (int i = 0; i < 16; ++i) { o0[i] *= corr; o1[i] *= corr; }
    }
    // P = exp2(S - m), pack to bf16 pairs (reg pairs are adjacent kv)
    unsigned pk0[8], pk1[8];
    float ls0 = 0.f, ls1 = 0.f;
#pragma unroll
    for (int i = 0; i < 8; ++i) {
      float a0 = exp2f(cur0[2 * i] - m), a1 = exp2f(cur0[2 * i + 1] - m);
      float b0 = exp2f(cur1[2 * i] - m), b1 = exp2f(cur1[2 * i + 1] - m);
      ls0 += a0 + a1;
      ls1 += b0 + b1;
      pk0[i] = cvtpk(a0, a1);
      pk1[i] = cvtpk(b0, b1);
    }
    l += ls0 + ls1;
    // ---- build PV B-frags: per kv-chunk c: 2 permlane32_swap ----
    bf16x8 pB[4];
#pragma unroll
    for (int c = 0; c < 4; ++c) {
      const int cl = c & 1;
      unsigned w0, w1, w2, w3;
      if (c < 2) { w0 = pk0[4 * cl + 0]; w1 = pk0[4 * cl + 1]; w2 = pk0[4 * cl + 2]; w3 = pk0[4 * cl + 3]; }
      else       { w0 = pk1[4 * cl + 0]; w1 = pk1[4 * cl + 1]; w2 = pk1[4 * cl + 2]; w3 = pk1[4 * cl + 3]; }
      pl32swap(w0, w2);
      pl32swap(w1, w3);
      uint4 bw;
      bw.x = w0; bw.y = w1; bw.z = w2; bw.w = w3;
      pB[c] = __builtin_bit_cast(bf16x8, bw);
    }
    // ---- O^T += V^T . P^T : A-frags from swizzled V tile ----
    const unsigned short* Vbuf = Vs[it % 3];
    const int x7 = l31 & 7;
    __builtin_amdgcn_s_setprio(1);
#pragma unroll
    for (int c = 0; c < 4; ++c) {
      const int ch = (2 * c + l5) ^ x7;
      bf16x8 va0 = *(const bf16x8*)&Vbuf[l31 * 64 + ch * 8];
      bf16x8 va1 = *(const bf16x8*)&Vbuf[(32 + l31) * 64 + ch * 8];
      o0 = MFMA32(va0, pB[c], o0);
      o1 = MFMA32(va1, pB[c], o1);
    }
    __builtin_amdgcn_s_setprio(0);
    __syncthreads();
    cur0 = nxt0;
    cur1 = nxt1;
  }

  // pair-reduce l; write RAW partial O (f32) + per-row (l, m)
  l += __shfl_xor(l, 32, 64);
  float* Od = half ? O2 : O1;
#pragma unroll
  for (int blk = 0; blk < 2; ++blk) {
#pragma unroll
    for (int rg = 0; rg < 4; ++rg) {
      const f32x16& o = blk ? o1 : o0;
      float4 u;
      u.x = o[4 * rg + 0];
      u.y = o[4 * rg + 1];
      u.z = o[4 * rg + 2];
      u.w = o[4 * rg + 3];
      const int dcol = 32 * blk + 8 * rg + 4 * l5;
      *(float4*)(Od + (size_t)(q0 + l31) * D + h * 64 + dcol) = u;
    }
  }
  if (lane < 32) {
    float2 lm;
    lm.x = l;
    lm.y = m;
    lmb[(size_t)(half * 16 + h) * S + q0 + l31] = lm;
  }
}

// ---------------------------------------------------------------------------
// Merge the two kv-half partials: O = (O1*2^(m1-M) + O2*2^(m2-M)) / (l1*.. + l2*..)
// grid 4096 (one block per q row), 256 threads x 4 cols.
// ---------------------------------------------------------------------------
__global__ __launch_bounds__(256) void attn_combine(const float* __restrict__ O1,
                                                    const float* __restrict__ O2,
                                                    const float2* __restrict__ lmb,
                                                    unsigned short* __restrict__ ab) {
  const int s = blockIdx.x, t = threadIdx.x;
  const int col = t * 4;
  const int h = col >> 6;
  float2 A = lmb[(size_t)h * S + s];
  float2 B = lmb[(size_t)(16 + h) * S + s];
  float M = fmaxf(A.y, B.y);
  float s1 = exp2f(A.y - M), s2 = exp2f(B.y - M);
  float invl = 1.0f / (A.x * s1 + B.x * s2);
  float4 a = *(const float4*)(O1 + (size_t)s * D + col);
  float4 b = *(const float4*)(O2 + (size_t)s * D + col);
  ushort4 u;
  u.x = f2bf((a.x * s1 + b.x * s2) * invl);
  u.y = f2bf((a.y * s1 + b.y * s2) * invl);
  u.z = f2bf((a.z * s1 + b.z * s2) * invl);
  u.w = f2bf((a.w * s1 + b.w * s2) * invl);
  *(ushort4*)(ab + (size_t)s * D + col) = u;
}

// ---------------------------------------------------------------------------
extern "C" void kernel_launch(void* const* d_in, const int* in_sizes, int n_in,
                              void* d_out, int out_size, void* d_ws, size_t ws_size,
                              hipStream_t stream) {
  const float* hidden = (const float*)d_in[0];
  const float* qkvw   = (const float*)d_in[1];
  const float* qkvb   = (const float*)d_in[2];
  const float* projw  = (const float*)d_in[3];
  const float* projb  = (const float*)d_in[4];
  const float* qnw    = (const float*)d_in[5];
  const float* knw    = (const float*)d_in[6];
  const float* freqs  = (const float*)d_in[7];
  float* out = (float*)d_out;
  char* ws = (char*)d_ws;

  unsigned short* hb  = (unsigned short*)(ws + 0);               // 8 MB  hidden bf16
  unsigned short* wb  = (unsigned short*)(ws + (8u << 20));      // 6 MB  qkv_w bf16
  unsigned short* pb  = (unsigned short*)(ws + (14u << 20));     // 2 MB  proj_w bf16
  unsigned short* qk  = (unsigned short*)(ws + (16u << 20));     // 16 MB q|k bf16 (dead after norm_rope)
  unsigned short* vtb = (unsigned short*)(ws + (32u << 20));     // 8 MB  v^T bf16 [16][64][4096]
  unsigned short* qb  = (unsigned short*)(ws + (40u << 20));     // 8 MB  q bf16 [16][4096][64]
  unsigned short* kb  = (unsigned short*)(ws + (48u << 20));     // 8 MB  k bf16 [16][4096][64]
  unsigned short* ab  = (unsigned short*)(ws + (56u << 20));     // 8 MB  attn bf16 [4096][1024]
  float*          Op1 = (float*)(ws + (16u << 20));              // 16 MB O half-0 f32 (overlays dead qk)
  float*          Op2 = (float*)(ws + (64u << 20));              // 16 MB O half-1 f32
  float2*         lmb = (float2*)(ws + (80u << 20));             // 1 MB  (l,m) per half/head/row

  cvt3<<<8192, 256, 0, stream>>>(hidden, hb, qkvw, wb, projw, pb);
  gemm_qkv<<<dim3(24, 32), 256, 0, stream>>>(hb, wb, qkvb, qk, vtb);
  norm_rope<<<4096, 256, 0, stream>>>(qk, qnw, knw, freqs, qb, kb);
  attn_kernel<<<1024, 256, 0, stream>>>(qb, kb, vtb, Op1, Op2, lmb);
  attn_combine<<<4096, 256, 0, stream>>>(Op1, Op2, lmb, ab);
  gemm_bt<<<dim3(8, 32), 256, 0, stream>>>(ab, pb, projb, out, 4096, 1024, 1024, 8);
}

// Round 18
// 115.499 us; speedup vs baseline: 1.0848x; 1.0848x over previous
//
#include <hip/hip_runtime.h>
#include <hip/hip_bf16.h>

#define S 4096
#define D 1024
#define NH 16
#define HD 64

typedef float f32x4 __attribute__((ext_vector_type(4)));
typedef float f32x16 __attribute__((ext_vector_type(16)));
typedef __bf16 bf16x8 __attribute__((ext_vector_type(8)));

#define MFMA16(a, b, c) __builtin_amdgcn_mfma_f32_16x16x32_bf16((a), (b), (c), 0, 0, 0)
#define MFMA32(a, b, c) __builtin_amdgcn_mfma_f32_32x32x16_bf16((a), (b), (c), 0, 0, 0)

__device__ __forceinline__ unsigned short f2bf(float f) {
  unsigned int u = __builtin_bit_cast(unsigned int, f);
  u += 0x7FFFu + ((u >> 16) & 1u);
  return (unsigned short)(u >> 16);
}

__device__ __forceinline__ float bf2f(unsigned short u) {
  unsigned int x = ((unsigned int)u) << 16;
  return __builtin_bit_cast(float, x);
}

__device__ __forceinline__ unsigned cvtpk(float lo, float hi) {
  unsigned r;
  asm("v_cvt_pk_bf16_f32 %0, %1, %2" : "=v"(r) : "v"(lo), "v"(hi));
  return r;
}

// exchange: a.hi-lanes <-> b.lo-lanes (a'[i>=32]=b[i-32], b'[i<32]=a[i+32])
__device__ __forceinline__ void pl32swap(unsigned& a, unsigned& b) {
#if __has_builtin(__builtin_amdgcn_permlane32_swap)
  typedef unsigned u32x2 __attribute__((ext_vector_type(2)));
  u32x2 r = __builtin_amdgcn_permlane32_swap(a, b, false, false);
  a = r.x;
  b = r.y;
#else
  asm volatile("v_permlane32_swap_b32 %0, %1" : "+v"(a), "+v"(b));
#endif
}

typedef __attribute__((address_space(1))) void GAS;
typedef __attribute__((address_space(3))) void LAS;

__device__ __forceinline__ void gld_lds16(const unsigned short* g, unsigned short* l) {
  __builtin_amdgcn_global_load_lds((GAS*)g, (LAS*)l, 16, 0, 0);
}

// ---------------------------------------------------------------------------
// fused f32 -> bf16 convert of hidden (1048576 f4), qkv_w (786432 f4),
// proj_w (262144 f4) in one launch. 8192 blocks x 256 threads.
// ---------------------------------------------------------------------------
__global__ void cvt3(const float* __restrict__ a, unsigned short* __restrict__ ao,
                     const float* __restrict__ b, unsigned short* __restrict__ bo,
                     const float* __restrict__ c, unsigned short* __restrict__ co) {
  int i = blockIdx.x * blockDim.x + threadIdx.x;
  const float* in;
  unsigned short* out;
  int j;
  if (i < 1048576) { in = a; out = ao; j = i; }
  else if (i < 1835008) { in = b; out = bo; j = i - 1048576; }
  else { in = c; out = co; j = i - 1835008; }
  float4 v = ((const float4*)in)[j];
  ushort4 u;
  u.x = f2bf(v.x); u.y = f2bf(v.y); u.z = f2bf(v.z); u.w = f2bf(v.w);
  ((ushort4*)out)[j] = u;
}

// bijective XCD swizzle of a linear block id (nwg % 8 == 0)
__device__ __forceinline__ int xcd_swz(int bid, int nwg) {
  int q = nwg >> 3;
  return (bid & 7) * q + (bid >> 3);
}

// --- Deep-pipelined K-step macros (K=1024, BK=32, 3 static buffer pairs) ----
#define DSTEP_S(RA, RB, SA, SB, KN, VM)                                          \
  {                                                                              \
    bf16x8 af[4], bfv[4];                                                        \
    _Pragma("unroll") for (int mf = 0; mf < 4; ++mf)                             \
        af[mf] = *(const bf16x8*)&RA[(wr * 64 + mf * 16 + l15) * 32 + l4 * 8];   \
    _Pragma("unroll") for (int nf = 0; nf < 4; ++nf)                             \
        bfv[nf] = *(const bf16x8*)&RB[(wc * 64 + nf * 16 + l15) * 32 + l4 * 8];  \
    gld_lds16(Ab + (size_t)r0 * 1024 + (KN) + o0, &SA[w * 512]);                 \
    gld_lds16(Ab + (size_t)r1 * 1024 + (KN) + o1, &SA[2048 + w * 512]);          \
    gld_lds16(Bb + (size_t)r0 * 1024 + (KN) + o0, &SB[w * 512]);                 \
    gld_lds16(Bb + (size_t)r1 * 1024 + (KN) + o1, &SB[2048 + w * 512]);          \
    _Pragma("unroll") for (int mf = 0; mf < 4; ++mf)                             \
        _Pragma("unroll") for (int nf = 0; nf < 4; ++nf)                         \
            acc[mf][nf] = MFMA16(af[mf], bfv[nf], acc[mf][nf]);                  \
    asm volatile("s_waitcnt vmcnt(" VM ")" ::: "memory");                        \
    __builtin_amdgcn_s_barrier();                                                \
  }

#define DSTEP_N(RA, RB, VM)                                                      \
  {                                                                              \
    bf16x8 af[4], bfv[4];                                                        \
    _Pragma("unroll") for (int mf = 0; mf < 4; ++mf)                             \
        af[mf] = *(const bf16x8*)&RA[(wr * 64 + mf * 16 + l15) * 32 + l4 * 8];   \
    _Pragma("unroll") for (int nf = 0; nf < 4; ++nf)                             \
        bfv[nf] = *(const bf16x8*)&RB[(wc * 64 + nf * 16 + l15) * 32 + l4 * 8];  \
    _Pragma("unroll") for (int mf = 0; mf < 4; ++mf)                             \
        _Pragma("unroll") for (int nf = 0; nf < 4; ++nf)                         \
            acc[mf][nf] = MFMA16(af[mf], bfv[nf], acc[mf][nf]);                  \
    asm volatile("s_waitcnt vmcnt(" VM ")" ::: "memory");                        \
    __builtin_amdgcn_s_barrier();                                                \
  }

#define DSTEP_LAST(RA, RB)                                                       \
  {                                                                              \
    bf16x8 af[4], bfv[4];                                                        \
    _Pragma("unroll") for (int mf = 0; mf < 4; ++mf)                             \
        af[mf] = *(const bf16x8*)&RA[(wr * 64 + mf * 16 + l15) * 32 + l4 * 8];   \
    _Pragma("unroll") for (int nf = 0; nf < 4; ++nf)                             \
        bfv[nf] = *(const bf16x8*)&RB[(wc * 64 + nf * 16 + l15) * 32 + l4 * 8];  \
    _Pragma("unroll") for (int mf = 0; mf < 4; ++mf)                             \
        _Pragma("unroll") for (int nf = 0; nf < 4; ++nf)                         \
            acc[mf][nf] = MFMA16(af[mf], bfv[nf], acc[mf][nf]);                  \
  }

#define GEMM_PRO_LOOP()                                                          \
  gld_lds16(Ab + (size_t)r0 * 1024 + o0, &As0[w * 512]);                         \
  gld_lds16(Ab + (size_t)r1 * 1024 + o1, &As0[2048 + w * 512]);                  \
  gld_lds16(Bb + (size_t)r0 * 1024 + o0, &Bs0[w * 512]);                         \
  gld_lds16(Bb + (size_t)r1 * 1024 + o1, &Bs0[2048 + w * 512]);                  \
  gld_lds16(Ab + (size_t)r0 * 1024 + 32 + o0, &As1[w * 512]);                    \
  gld_lds16(Ab + (size_t)r1 * 1024 + 32 + o1, &As1[2048 + w * 512]);             \
  gld_lds16(Bb + (size_t)r0 * 1024 + 32 + o0, &Bs1[w * 512]);                    \
  gld_lds16(Bb + (size_t)r1 * 1024 + 32 + o1, &Bs1[2048 + w * 512]);             \
  asm volatile("s_waitcnt vmcnt(4)" ::: "memory");                               \
  __builtin_amdgcn_s_barrier();                                                  \
  _Pragma("unroll 1") for (int k0 = 0; k0 < 960; k0 += 96) {                     \
    DSTEP_S(As0, Bs0, As2, Bs2, k0 + 64, "4")                                    \
    DSTEP_S(As1, Bs1, As0, Bs0, k0 + 96, "4")                                    \
    DSTEP_S(As2, Bs2, As1, Bs1, k0 + 128, "4")                                   \
  }                                                                              \
  DSTEP_N(As0, Bs0, "0")                                                         \
  DSTEP_LAST(As1, Bs1)

// ---------------------------------------------------------------------------
// QKV GEMM: qkv[4096 x 3072] = hidden @ qkv_w^T + b. L2-partitioned per XCD.
// 3-deep counted-vmcnt pipelined K-loop, launch_bounds(256,3) -> 3 blocks/CU.
// ---------------------------------------------------------------------------
__global__ __launch_bounds__(256, 3) void gemm_qkv(const unsigned short* __restrict__ A,
                                                   const unsigned short* __restrict__ B,
                                                   const float* __restrict__ bias,
                                                   unsigned short* __restrict__ qk,
                                                   unsigned short* __restrict__ vt) {
  __shared__ __align__(16) unsigned short As0[4096], As1[4096], As2[4096];
  __shared__ __align__(16) unsigned short Bs0[4096], Bs1[4096], Bs2[4096];
  __shared__ __align__(16) unsigned short tr[128 * 17];  // 16-col transpose chunk
  const int t = threadIdx.x;
  const int lane = t & 63;
  const int w = t >> 6;
  const int wr = w >> 1, wc = w & 1;
  const int l15 = lane & 15, l4 = lane >> 4;
  const int bid = blockIdx.y * 24 + blockIdx.x;
  const int r8 = bid & 7, i = bid >> 3;
  const int by = (r8 >> 1) * 8 + i / 12;
  const int bx = (r8 & 1) * 12 + i % 12;
  const int m0 = by * 128, n0 = bx * 128;

  f32x4 acc[4][4] = {};

  const int r0 = t >> 2, o0 = (t & 3) * 8;
  const int r1 = (256 + t) >> 2, o1 = ((256 + t) & 3) * 8;
  const unsigned short* Ab = A + (size_t)m0 * 1024;
  const unsigned short* Bb = B + (size_t)n0 * 1024;

  GEMM_PRO_LOOP()

  if (n0 < 2048) {
#pragma unroll
    for (int mf = 0; mf < 4; ++mf)
#pragma unroll
      for (int nf = 0; nf < 4; ++nf) {
        int rr = m0 + wr * 64 + mf * 16 + l4 * 4;
        int cc = n0 + wc * 64 + nf * 16 + l15;
        float bv = bias[cc];
#pragma unroll
        for (int j = 0; j < 4; ++j)
          qk[(size_t)(rr + j) * 2048 + cc] = f2bf(acc[mf][nf][j] + bv);
      }
  } else {
    const int h0 = (n0 - 2048) >> 6;
#pragma unroll
    for (int ch = 0; ch < 8; ++ch) {
      __syncthreads();
      if (wc == (ch >> 2)) {
        const int nf = ch & 3;
        const float bv = bias[n0 + (ch >> 2) * 64 + nf * 16 + l15];
#pragma unroll
        for (int mf = 0; mf < 4; ++mf) {
          int srow = wr * 64 + mf * 16 + l4 * 4;
#pragma unroll
          for (int j = 0; j < 4; ++j)
            tr[(srow + j) * 17 + l15] = f2bf(acc[mf][nf][j] + bv);
        }
      }
      __syncthreads();
      const int hh = h0 + (ch >> 2);
      const int dbase = (ch & 3) * 16;
#pragma unroll
      for (int i2 = 0; i2 < 2; ++i2) {
        int g = i2 * 256 + t;
        int dp = g >> 5, sg = g & 31;
        ushort4 u;
        u.x = tr[(sg * 4 + 0) * 17 + dp];
        u.y = tr[(sg * 4 + 1) * 17 + dp];
        u.z = tr[(sg * 4 + 2) * 17 + dp];
        u.w = tr[(sg * 4 + 3) * 17 + dp];
        *(ushort4*)(vt + (size_t)hh * HD * S + (size_t)(dbase + dp) * S + m0 + sg * 4) = u;
      }
    }
  }
}

// ---------------------------------------------------------------------------
// proj GEMM: out f32 = A bf16 @ B^T bf16 + bias. Same pipelined K-loop.
// ---------------------------------------------------------------------------
__global__ __launch_bounds__(256, 3) void gemm_bt(const unsigned short* __restrict__ A,
                                                  const unsigned short* __restrict__ B,
                                                  const float* __restrict__ bias,
                                                  float* __restrict__ C,
                                                  int M, int N, int K, int gx) {
  __shared__ __align__(16) unsigned short As0[4096], As1[4096], As2[4096];
  __shared__ __align__(16) unsigned short Bs0[4096], Bs1[4096], Bs2[4096];
  const int t = threadIdx.x;
  const int lane = t & 63;
  const int w = t >> 6;
  const int wr = w >> 1, wc = w & 1;
  const int l15 = lane & 15, l4 = lane >> 4;
  const int nwg = gridDim.x * gridDim.y;
  const int nbid = xcd_swz(blockIdx.y * gx + blockIdx.x, nwg);
  const int m0 = (nbid / gx) * 128, n0 = (nbid % gx) * 128;

  f32x4 acc[4][4] = {};

  const int r0 = t >> 2, o0 = (t & 3) * 8;
  const int r1 = (256 + t) >> 2, o1 = ((256 + t) & 3) * 8;
  const unsigned short* Ab = A + (size_t)m0 * 1024;
  const unsigned short* Bb = B + (size_t)n0 * 1024;

  GEMM_PRO_LOOP()

#pragma unroll
  for (int mf = 0; mf < 4; ++mf) {
#pragma unroll
    for (int nf = 0; nf < 4; ++nf) {
      int rr = m0 + wr * 64 + mf * 16 + l4 * 4;
      int cc = n0 + wc * 64 + nf * 16 + l15;
      float bv = bias[cc];
#pragma unroll
      for (int j = 0; j < 4; ++j)
        C[(size_t)(rr + j) * N + cc] = acc[mf][nf][j] + bv;
    }
  }
}

// ---------------------------------------------------------------------------
// Per-row RMSNorm + RoPE from bf16 qk rows -> head-major q/k [NH][S][HD].
// q scaled by 0.125*log2(e) (softmax in exp2 space).
// ---------------------------------------------------------------------------
__global__ __launch_bounds__(256) void norm_rope(const unsigned short* __restrict__ qk,
                                                 const float* __restrict__ qw,
                                                 const float* __restrict__ kw,
                                                 const float* __restrict__ fr,
                                                 unsigned short* __restrict__ qo,
                                                 unsigned short* __restrict__ ko) {
  __shared__ float buf[1024];
  __shared__ float red[4];
  const int s = blockIdx.x, t = threadIdx.x;
  const int lane = t & 63, w = t >> 6;
  const int e = t * 4;
  const int hh = e >> 6, dd = e & 63;
  const float* frow = fr + (size_t)s * 32;
  float cs[4], sn[4];
#pragma unroll
  for (int i = 0; i < 4; ++i) {
    float f = frow[(dd + i) & 31];
    cs[i] = cosf(f);
    sn[i] = sinf(f);
  }
  for (int part = 0; part < 2; ++part) {
    const unsigned short* row = qk + (size_t)s * 2048 + part * 1024;
    const float* wvp = part ? kw : qw;
    unsigned short* op = part ? ko : qo;
    const float oscale = part ? 1.0f : 0.18033688011112042f;
    ushort4 uv = *(const ushort4*)(row + e);
    float vx = bf2f(uv.x), vy = bf2f(uv.y), vz = bf2f(uv.z), vw = bf2f(uv.w);
    float ssq = vx * vx + vy * vy + vz * vz + vw * vw;
#pragma unroll
    for (int off = 1; off < 64; off <<= 1) ssq += __shfl_xor(ssq, off, 64);
    if (part) __syncthreads();
    if (lane == 0) red[w] = ssq;
    __syncthreads();
    float inv = rsqrtf((red[0] + red[1] + red[2] + red[3]) * (1.0f / 1024.0f) + 1e-6f);
    float4 wv = *(const float4*)(wvp + e);
    buf[e + 0] = vx * inv * wv.x;
    buf[e + 1] = vy * inv * wv.y;
    buf[e + 2] = vz * inv * wv.z;
    buf[e + 3] = vw * inv * wv.w;
    __syncthreads();
    unsigned short ov[4];
#pragma unroll
    for (int i = 0; i < 4; ++i) {
      int di = dd + i;
      float x = buf[e + i];
      float rot = (di < 32) ? -buf[e + i + 32] : buf[e + i - 32];
      ov[i] = f2bf((x * cs[i] + rot * sn[i]) * oscale);
    }
    unsigned short* dst = op + (size_t)hh * S * HD + (size_t)s * HD + dd;
    dst[0] = ov[0]; dst[1] = ov[1]; dst[2] = ov[2]; dst[3] = ov[3];
  }
}

// ---------------------------------------------------------------------------
// QK^T (32x32): S^T[kv 64][q 32] += K . Q^T from swizzled [64][64] K LDS tile.
// ---------------------------------------------------------------------------
__device__ __forceinline__ void qk_tile32(f32x16& s0, f32x16& s1,
                                          const unsigned short* Kbuf,
                                          const bf16x8* qB, int l31, int l5) {
  const int x7 = l31 & 7;
#pragma unroll
  for (int c = 0; c < 4; ++c) {
    const int ch = (2 * c + l5) ^ x7;
    bf16x8 ka0 = *(const bf16x8*)&Kbuf[l31 * 64 + ch * 8];
    bf16x8 ka1 = *(const bf16x8*)&Kbuf[(32 + l31) * 64 + ch * 8];
    s0 = MFMA32(ka0, qB[c], s0);
    s1 = MFMA32(ka1, qB[c], s1);
  }
}

// ---------------------------------------------------------------------------
// Flash attention, 32x32 MFMA, 4 waves x 32 q-rows (block = 128 q-rows).
// Swapped QK^T; in-register softmax (defer-max with __all gate); P->B-frags
// via cvt_pk + permlane32_swap. 2-deep QK pipeline, K dbuf + V 3-ring.
// grid: 512 = XCD-grouped (h,seg) x 8 q-tiles of 128.  [round-14 version]
// ---------------------------------------------------------------------------
__global__ __launch_bounds__(256) void attn_kernel(const unsigned short* __restrict__ q,
                                                   const unsigned short* __restrict__ k,
                                                   const unsigned short* __restrict__ vt,
                                                   unsigned short* __restrict__ aout) {
  __shared__ __align__(16) unsigned short Ks[2][4096];
  __shared__ __align__(16) unsigned short Vs[3][4096];
  const int bid = blockIdx.x;
  const int xcd = bid & 7;
  const int idx = bid >> 3;
  const int gw = idx >> 3, qt = idx & 7;
  const int g = xcd * 8 + gw;
  const int h = g >> 2, seg = g & 3;
  const int t = threadIdx.x, lane = t & 63, w = t >> 6;
  const int l31 = lane & 31, l5 = lane >> 5;
  const size_t hb = (size_t)h * S * HD;
  const int q0 = seg * 1024 + qt * 128 + w * 32;
  const int kvbase = seg * 1024;

  const int sr = t >> 3;               // tile row 0..31
  const int scb = (t & 7) ^ (sr & 7);  // swizzled source column-chunk
  const unsigned short* ksrcA = k + hb + (size_t)(kvbase + sr) * HD + scb * 8;
  const unsigned short* ksrcB = ksrcA + 32 * HD;
  const unsigned short* vsrcA = vt + (size_t)h * HD * S + (size_t)sr * S + kvbase + scb * 8;
  const unsigned short* vsrcB = vsrcA + (size_t)32 * S;

  // Q B-frags: 4 d-chunks of 16
  const unsigned short* qp = q + hb + (size_t)(q0 + l31) * HD + l5 * 8;
  bf16x8 qB[4];
#pragma unroll
  for (int c = 0; c < 4; ++c) qB[c] = *(const bf16x8*)(qp + 16 * c);

  f32x16 o0 = {}, o1 = {};
  float m = -1e30f, l = 0.f;

  // prologue: stage K0,K1,V0,V1
  gld_lds16(ksrcA, &Ks[0][w * 512]);
  gld_lds16(ksrcB, &Ks[0][2048 + w * 512]);
  gld_lds16(ksrcA + 4096, &Ks[1][w * 512]);
  gld_lds16(ksrcB + 4096, &Ks[1][2048 + w * 512]);
  gld_lds16(vsrcA, &Vs[0][w * 512]);
  gld_lds16(vsrcB, &Vs[0][2048 + w * 512]);
  gld_lds16(vsrcA + 64, &Vs[1][w * 512]);
  gld_lds16(vsrcB + 64, &Vs[1][2048 + w * 512]);
  __syncthreads();

  f32x16 cur0 = {}, cur1 = {};
  qk_tile32(cur0, cur1, Ks[0], qB, l31, l5);
  __syncthreads();  // tile-0 K reads retired before iter0 overwrites Ks[0]

#pragma unroll
  for (int it = 0; it < 16; ++it) {
    // stage tile it+2
    if (it < 14) {
      gld_lds16(ksrcA + (it + 2) * 4096, &Ks[it & 1][w * 512]);
      gld_lds16(ksrcB + (it + 2) * 4096, &Ks[it & 1][2048 + w * 512]);
      gld_lds16(vsrcA + (it + 2) * 64, &Vs[(it + 2) % 3][w * 512]);
      gld_lds16(vsrcB + (it + 2) * 64, &Vs[(it + 2) % 3][2048 + w * 512]);
    }
    // issue QK MFMAs for tile it+1 (consumed next iteration)
    f32x16 nxt0 = {}, nxt1 = {};
    if (it < 15) {
      __builtin_amdgcn_s_setprio(1);
      qk_tile32(nxt0, nxt1, Ks[(it + 1) & 1], qB, l31, l5);
      __builtin_amdgcn_s_setprio(0);
      __builtin_amdgcn_sched_barrier(0);
    }
    // ---- in-register softmax on cur (32 values/lane), exp2, defer-max ----
    float mm[16];
#pragma unroll
    for (int i = 0; i < 16; ++i) mm[i] = fmaxf(cur0[i], cur1[i]);
#pragma unroll
    for (int st = 8; st > 0; st >>= 1)
#pragma unroll
      for (int i = 0; i < 8; ++i)
        if (i < st) mm[i] = fmaxf(mm[i], mm[i + st]);
    float lmax = fmaxf(mm[0], __shfl_xor(mm[0], 32, 64));
    if (!__all(lmax <= m + 8.0f)) {  // rescale (always on it==0)
      const float mn = fmaxf(m, lmax);
      const float corr = exp2f(m - mn);
      m = mn;
      l *= corr;
#pragma unroll
      for (int i = 0; i < 16; ++i) { o0[i] *= corr; o1[i] *= corr; }
    }
    // P = exp2(S - m), pack to bf16 pairs (reg pairs are adjacent kv)
    unsigned pk0[8], pk1[8];
    float ls0 = 0.f, ls1 = 0.f;
#pragma unroll
    for (int i = 0; i < 8; ++i) {
      float a0 = exp2f(cur0[2 * i] - m), a1 = exp2f(cur0[2 * i + 1] - m);
      float b0 = exp2f(cur1[2 * i] - m), b1 = exp2f(cur1[2 * i + 1] - m);
      ls0 += a0 + a1;
      ls1 += b0 + b1;
      pk0[i] = cvtpk(a0, a1);
      pk1[i] = cvtpk(b0, b1);
    }
    l += ls0 + ls1;
    // ---- build PV B-frags: per kv-chunk c: 2 permlane32_swap ----
    bf16x8 pB[4];
#pragma unroll
    for (int c = 0; c < 4; ++c) {
      const int cl = c & 1;
      unsigned w0, w1, w2, w3;
      if (c < 2) { w0 = pk0[4 * cl + 0]; w1 = pk0[4 * cl + 1]; w2 = pk0[4 * cl + 2]; w3 = pk0[4 * cl + 3]; }
      else       { w0 = pk1[4 * cl + 0]; w1 = pk1[4 * cl + 1]; w2 = pk1[4 * cl + 2]; w3 = pk1[4 * cl + 3]; }
      pl32swap(w0, w2);
      pl32swap(w1, w3);
      uint4 bw;
      bw.x = w0; bw.y = w1; bw.z = w2; bw.w = w3;
      pB[c] = __builtin_bit_cast(bf16x8, bw);
    }
    // ---- O^T += V^T . P^T : A-frags from swizzled V tile ----
    const unsigned short* Vbuf = Vs[it % 3];
    const int x7 = l31 & 7;
    __builtin_amdgcn_s_setprio(1);
#pragma unroll
    for (int c = 0; c < 4; ++c) {
      const int ch = (2 * c + l5) ^ x7;
      bf16x8 va0 = *(const bf16x8*)&Vbuf[l31 * 64 + ch * 8];
      bf16x8 va1 = *(const bf16x8*)&Vbuf[(32 + l31) * 64 + ch * 8];
      o0 = MFMA32(va0, pB[c], o0);
      o1 = MFMA32(va1, pB[c], o1);
    }
    __builtin_amdgcn_s_setprio(0);
    __syncthreads();
    cur0 = nxt0;
    cur1 = nxt1;
  }

  // final l reduce across the 32-half pair, then epilogue
  l += __shfl_xor(l, 32, 64);
  const float invl = 1.0f / l;
#pragma unroll
  for (int blk = 0; blk < 2; ++blk) {
#pragma unroll
    for (int rg = 0; rg < 4; ++rg) {
      const f32x16& o = blk ? o1 : o0;
      ushort4 u;
      u.x = f2bf(o[4 * rg + 0] * invl);
      u.y = f2bf(o[4 * rg + 1] * invl);
      u.z = f2bf(o[4 * rg + 2] * invl);
      u.w = f2bf(o[4 * rg + 3] * invl);
      const int dcol = 32 * blk + 8 * rg + 4 * l5;
      *(ushort4*)(aout + (size_t)(q0 + l31) * D + h * 64 + dcol) = u;
    }
  }
}

// ---------------------------------------------------------------------------
extern "C" void kernel_launch(void* const* d_in, const int* in_sizes, int n_in,
                              void* d_out, int out_size, void* d_ws, size_t ws_size,
                              hipStream_t stream) {
  const float* hidden = (const float*)d_in[0];
  const float* qkvw   = (const float*)d_in[1];
  const float* qkvb   = (const float*)d_in[2];
  const float* projw  = (const float*)d_in[3];
  const float* projb  = (const float*)d_in[4];
  const float* qnw    = (const float*)d_in[5];
  const float* knw    = (const float*)d_in[6];
  const float* freqs  = (const float*)d_in[7];
  float* out = (float*)d_out;
  char* ws = (char*)d_ws;

  unsigned short* hb  = (unsigned short*)(ws + 0);               // 8 MB  hidden bf16
  unsigned short* wb  = (unsigned short*)(ws + (8u << 20));      // 6 MB  qkv_w bf16
  unsigned short* pb  = (unsigned short*)(ws + (14u << 20));     // 2 MB  proj_w bf16
  unsigned short* qk  = (unsigned short*)(ws + (16u << 20));     // 16 MB q|k bf16 [4096][2048]
  unsigned short* vtb = (unsigned short*)(ws + (32u << 20));     // 8 MB  v^T bf16 [16][64][4096]
  unsigned short* qb  = (unsigned short*)(ws + (40u << 20));     // 8 MB  q bf16 [16][4096][64]
  unsigned short* kb  = (unsigned short*)(ws + (48u << 20));     // 8 MB  k bf16 [16][4096][64]
  unsigned short* ab  = (unsigned short*)(ws + (56u << 20));     // 8 MB  attn bf16 [4096][1024]

  cvt3<<<8192, 256, 0, stream>>>(hidden, hb, qkvw, wb, projw, pb);
  gemm_qkv<<<dim3(24, 32), 256, 0, stream>>>(hb, wb, qkvb, qk, vtb);
  norm_rope<<<4096, 256, 0, stream>>>(qk, qnw, knw, freqs, qb, kb);
  attn_kernel<<<512, 256, 0, stream>>>(qb, kb, vtb, ab);
  gemm_bt<<<dim3(8, 32), 256, 0, stream>>>(ab, pb, projb, out, 4096, 1024, 1024, 8);
}

// Round 19
// 115.001 us; speedup vs baseline: 1.0895x; 1.0043x over previous
//
#include <hip/hip_runtime.h>
#include <hip/hip_bf16.h>

#define S 4096
#define D 1024
#define NH 16
#define HD 64

typedef float f32x4 __attribute__((ext_vector_type(4)));
typedef float f32x16 __attribute__((ext_vector_type(16)));
typedef __bf16 bf16x8 __attribute__((ext_vector_type(8)));

#define MFMA16(a, b, c) __builtin_amdgcn_mfma_f32_16x16x32_bf16((a), (b), (c), 0, 0, 0)
#define MFMA32(a, b, c) __builtin_amdgcn_mfma_f32_32x32x16_bf16((a), (b), (c), 0, 0, 0)

__device__ __forceinline__ unsigned short f2bf(float f) {
  unsigned int u = __builtin_bit_cast(unsigned int, f);
  u += 0x7FFFu + ((u >> 16) & 1u);
  return (unsigned short)(u >> 16);
}

__device__ __forceinline__ float bf2f(unsigned short u) {
  unsigned int x = ((unsigned int)u) << 16;
  return __builtin_bit_cast(float, x);
}

__device__ __forceinline__ unsigned cvtpk(float lo, float hi) {
  unsigned r;
  asm("v_cvt_pk_bf16_f32 %0, %1, %2" : "=v"(r) : "v"(lo), "v"(hi));
  return r;
}

// exchange: a.hi-lanes <-> b.lo-lanes (a'[i>=32]=b[i-32], b'[i<32]=a[i+32])
__device__ __forceinline__ void pl32swap(unsigned& a, unsigned& b) {
#if __has_builtin(__builtin_amdgcn_permlane32_swap)
  typedef unsigned u32x2 __attribute__((ext_vector_type(2)));
  u32x2 r = __builtin_amdgcn_permlane32_swap(a, b, false, false);
  a = r.x;
  b = r.y;
#else
  asm volatile("v_permlane32_swap_b32 %0, %1" : "+v"(a), "+v"(b));
#endif
}

typedef __attribute__((address_space(1))) void GAS;
typedef __attribute__((address_space(3))) void LAS;

__device__ __forceinline__ void gld_lds16(const unsigned short* g, unsigned short* l) {
  __builtin_amdgcn_global_load_lds((GAS*)g, (LAS*)l, 16, 0, 0);
}

// ---------------------------------------------------------------------------
// fused f32 -> bf16 convert of hidden (1048576 f4), qkv_w (786432 f4),
// proj_w (262144 f4) in one launch. 8192 blocks x 256 threads.
// ---------------------------------------------------------------------------
__global__ void cvt3(const float* __restrict__ a, unsigned short* __restrict__ ao,
                     const float* __restrict__ b, unsigned short* __restrict__ bo,
                     const float* __restrict__ c, unsigned short* __restrict__ co) {
  int i = blockIdx.x * blockDim.x + threadIdx.x;
  const float* in;
  unsigned short* out;
  int j;
  if (i < 1048576) { in = a; out = ao; j = i; }
  else if (i < 1835008) { in = b; out = bo; j = i - 1048576; }
  else { in = c; out = co; j = i - 1835008; }
  float4 v = ((const float4*)in)[j];
  ushort4 u;
  u.x = f2bf(v.x); u.y = f2bf(v.y); u.z = f2bf(v.z); u.w = f2bf(v.w);
  ((ushort4*)out)[j] = u;
}

// bijective XCD swizzle of a linear block id (nwg % 8 == 0)
__device__ __forceinline__ int xcd_swz(int bid, int nwg) {
  int q = nwg >> 3;
  return (bid & 7) * q + (bid >> 3);
}

// --- Deep-pipelined K-step macros (K=1024, BK=32, 3 static buffer pairs) ----
// LDS tiles are chunk-XOR swizzled (bank-conflict fix, 8-way -> 4-way):
// LDS[r][c] holds X[r][c ^ (r&3)]; staging pre-swizzles the GLOBAL source
// chunk (o0==o1== ((t&3)^((t>>2)&3))*8, LDS dest stays linear for
// global_load_lds); reads use csw = (l4 ^ (l15&3))*8 (row&3 == l15&3).
#define DSTEP_S(RA, RB, SA, SB, KN, VM)                                          \
  {                                                                              \
    bf16x8 af[4], bfv[4];                                                        \
    _Pragma("unroll") for (int mf = 0; mf < 4; ++mf)                             \
        af[mf] = *(const bf16x8*)&RA[(wr * 64 + mf * 16 + l15) * 32 + csw];      \
    _Pragma("unroll") for (int nf = 0; nf < 4; ++nf)                             \
        bfv[nf] = *(const bf16x8*)&RB[(wc * 64 + nf * 16 + l15) * 32 + csw];     \
    gld_lds16(Ab + (size_t)r0 * 1024 + (KN) + o0, &SA[w * 512]);                 \
    gld_lds16(Ab + (size_t)r1 * 1024 + (KN) + o1, &SA[2048 + w * 512]);          \
    gld_lds16(Bb + (size_t)r0 * 1024 + (KN) + o0, &SB[w * 512]);                 \
    gld_lds16(Bb + (size_t)r1 * 1024 + (KN) + o1, &SB[2048 + w * 512]);          \
    _Pragma("unroll") for (int mf = 0; mf < 4; ++mf)                             \
        _Pragma("unroll") for (int nf = 0; nf < 4; ++nf)                         \
            acc[mf][nf] = MFMA16(af[mf], bfv[nf], acc[mf][nf]);                  \
    asm volatile("s_waitcnt vmcnt(" VM ")" ::: "memory");                        \
    __builtin_amdgcn_s_barrier();                                                \
  }

#define DSTEP_N(RA, RB, VM)                                                      \
  {                                                                              \
    bf16x8 af[4], bfv[4];                                                        \
    _Pragma("unroll") for (int mf = 0; mf < 4; ++mf)                             \
        af[mf] = *(const bf16x8*)&RA[(wr * 64 + mf * 16 + l15) * 32 + csw];      \
    _Pragma("unroll") for (int nf = 0; nf < 4; ++nf)                             \
        bfv[nf] = *(const bf16x8*)&RB[(wc * 64 + nf * 16 + l15) * 32 + csw];     \
    _Pragma("unroll") for (int mf = 0; mf < 4; ++mf)                             \
        _Pragma("unroll") for (int nf = 0; nf < 4; ++nf)                         \
            acc[mf][nf] = MFMA16(af[mf], bfv[nf], acc[mf][nf]);                  \
    asm volatile("s_waitcnt vmcnt(" VM ")" ::: "memory");                        \
    __builtin_amdgcn_s_barrier();                                                \
  }

#define DSTEP_LAST(RA, RB)                                                       \
  {                                                                              \
    bf16x8 af[4], bfv[4];                                                        \
    _Pragma("unroll") for (int mf = 0; mf < 4; ++mf)                             \
        af[mf] = *(const bf16x8*)&RA[(wr * 64 + mf * 16 + l15) * 32 + csw];      \
    _Pragma("unroll") for (int nf = 0; nf < 4; ++nf)                             \
        bfv[nf] = *(const bf16x8*)&RB[(wc * 64 + nf * 16 + l15) * 32 + csw];     \
    _Pragma("unroll") for (int mf = 0; mf < 4; ++mf)                             \
        _Pragma("unroll") for (int nf = 0; nf < 4; ++nf)                         \
            acc[mf][nf] = MFMA16(af[mf], bfv[nf], acc[mf][nf]);                  \
  }

#define GEMM_PRO_LOOP()                                                          \
  gld_lds16(Ab + (size_t)r0 * 1024 + o0, &As0[w * 512]);                         \
  gld_lds16(Ab + (size_t)r1 * 1024 + o1, &As0[2048 + w * 512]);                  \
  gld_lds16(Bb + (size_t)r0 * 1024 + o0, &Bs0[w * 512]);                         \
  gld_lds16(Bb + (size_t)r1 * 1024 + o1, &Bs0[2048 + w * 512]);                  \
  gld_lds16(Ab + (size_t)r0 * 1024 + 32 + o0, &As1[w * 512]);                    \
  gld_lds16(Ab + (size_t)r1 * 1024 + 32 + o1, &As1[2048 + w * 512]);             \
  gld_lds16(Bb + (size_t)r0 * 1024 + 32 + o0, &Bs1[w * 512]);                    \
  gld_lds16(Bb + (size_t)r1 * 1024 + 32 + o1, &Bs1[2048 + w * 512]);             \
  asm volatile("s_waitcnt vmcnt(4)" ::: "memory");                               \
  __builtin_amdgcn_s_barrier();                                                  \
  _Pragma("unroll 1") for (int k0 = 0; k0 < 960; k0 += 96) {                     \
    DSTEP_S(As0, Bs0, As2, Bs2, k0 + 64, "4")                                    \
    DSTEP_S(As1, Bs1, As0, Bs0, k0 + 96, "4")                                    \
    DSTEP_S(As2, Bs2, As1, Bs1, k0 + 128, "4")                                   \
  }                                                                              \
  DSTEP_N(As0, Bs0, "0")                                                         \
  DSTEP_LAST(As1, Bs1)

// ---------------------------------------------------------------------------
// QKV GEMM: qkv[4096 x 3072] = hidden @ qkv_w^T + b. L2-partitioned per XCD.
// 3-deep counted-vmcnt pipelined K-loop, launch_bounds(256,3) -> 3 blocks/CU.
// LDS chunk-XOR swizzle on staging/read (bank-conflict 8-way -> 4-way).
// ---------------------------------------------------------------------------
__global__ __launch_bounds__(256, 3) void gemm_qkv(const unsigned short* __restrict__ A,
                                                   const unsigned short* __restrict__ B,
                                                   const float* __restrict__ bias,
                                                   unsigned short* __restrict__ qk,
                                                   unsigned short* __restrict__ vt) {
  __shared__ __align__(16) unsigned short As0[4096], As1[4096], As2[4096];
  __shared__ __align__(16) unsigned short Bs0[4096], Bs1[4096], Bs2[4096];
  __shared__ __align__(16) unsigned short tr[128 * 17];  // 16-col transpose chunk
  const int t = threadIdx.x;
  const int lane = t & 63;
  const int w = t >> 6;
  const int wr = w >> 1, wc = w & 1;
  const int l15 = lane & 15, l4 = lane >> 4;
  const int bid = blockIdx.y * 24 + blockIdx.x;
  const int r8 = bid & 7, i = bid >> 3;
  const int by = (r8 >> 1) * 8 + i / 12;
  const int bx = (r8 & 1) * 12 + i % 12;
  const int m0 = by * 128, n0 = bx * 128;

  f32x4 acc[4][4] = {};

  const int r0 = t >> 2;
  const int r1 = 64 + (t >> 2);
  const int o0 = (((t & 3) ^ ((t >> 2) & 3))) * 8;  // pre-swizzled source chunk
  const int o1 = o0;                                // (256+t)&3 == t&3, same row&3
  const int csw = (l4 ^ (l15 & 3)) * 8;             // swizzled read chunk
  const unsigned short* Ab = A + (size_t)m0 * 1024;
  const unsigned short* Bb = B + (size_t)n0 * 1024;

  GEMM_PRO_LOOP()

  if (n0 < 2048) {
#pragma unroll
    for (int mf = 0; mf < 4; ++mf)
#pragma unroll
      for (int nf = 0; nf < 4; ++nf) {
        int rr = m0 + wr * 64 + mf * 16 + l4 * 4;
        int cc = n0 + wc * 64 + nf * 16 + l15;
        float bv = bias[cc];
#pragma unroll
        for (int j = 0; j < 4; ++j)
          qk[(size_t)(rr + j) * 2048 + cc] = f2bf(acc[mf][nf][j] + bv);
      }
  } else {
    const int h0 = (n0 - 2048) >> 6;
#pragma unroll
    for (int ch = 0; ch < 8; ++ch) {
      __syncthreads();
      if (wc == (ch >> 2)) {
        const int nf = ch & 3;
        const float bv = bias[n0 + (ch >> 2) * 64 + nf * 16 + l15];
#pragma unroll
        for (int mf = 0; mf < 4; ++mf) {
          int srow = wr * 64 + mf * 16 + l4 * 4;
#pragma unroll
          for (int j = 0; j < 4; ++j)
            tr[(srow + j) * 17 + l15] = f2bf(acc[mf][nf][j] + bv);
        }
      }
      __syncthreads();
      const int hh = h0 + (ch >> 2);
      const int dbase = (ch & 3) * 16;
#pragma unroll
      for (int i2 = 0; i2 < 2; ++i2) {
        int g = i2 * 256 + t;
        int dp = g >> 5, sg = g & 31;
        ushort4 u;
        u.x = tr[(sg * 4 + 0) * 17 + dp];
        u.y = tr[(sg * 4 + 1) * 17 + dp];
        u.z = tr[(sg * 4 + 2) * 17 + dp];
        u.w = tr[(sg * 4 + 3) * 17 + dp];
        *(ushort4*)(vt + (size_t)hh * HD * S + (size_t)(dbase + dp) * S + m0 + sg * 4) = u;
      }
    }
  }
}

// ---------------------------------------------------------------------------
// proj GEMM: out f32 = A bf16 @ B^T bf16 + bias. Same pipelined K-loop +
// LDS chunk-XOR swizzle.
// ---------------------------------------------------------------------------
__global__ __launch_bounds__(256, 3) void gemm_bt(const unsigned short* __restrict__ A,
                                                  const unsigned short* __restrict__ B,
                                                  const float* __restrict__ bias,
                                                  float* __restrict__ C,
                                                  int M, int N, int K, int gx) {
  __shared__ __align__(16) unsigned short As0[4096], As1[4096], As2[4096];
  __shared__ __align__(16) unsigned short Bs0[4096], Bs1[4096], Bs2[4096];
  const int t = threadIdx.x;
  const int lane = t & 63;
  const int w = t >> 6;
  const int wr = w >> 1, wc = w & 1;
  const int l15 = lane & 15, l4 = lane >> 4;
  const int nwg = gridDim.x * gridDim.y;
  const int nbid = xcd_swz(blockIdx.y * gx + blockIdx.x, nwg);
  const int m0 = (nbid / gx) * 128, n0 = (nbid % gx) * 128;

  f32x4 acc[4][4] = {};

  const int r0 = t >> 2;
  const int r1 = 64 + (t >> 2);
  const int o0 = (((t & 3) ^ ((t >> 2) & 3))) * 8;
  const int o1 = o0;
  const int csw = (l4 ^ (l15 & 3)) * 8;
  const unsigned short* Ab = A + (size_t)m0 * 1024;
  const unsigned short* Bb = B + (size_t)n0 * 1024;

  GEMM_PRO_LOOP()

#pragma unroll
  for (int mf = 0; mf < 4; ++mf) {
#pragma unroll
    for (int nf = 0; nf < 4; ++nf) {
      int rr = m0 + wr * 64 + mf * 16 + l4 * 4;
      int cc = n0 + wc * 64 + nf * 16 + l15;
      float bv = bias[cc];
#pragma unroll
      for (int j = 0; j < 4; ++j)
        C[(size_t)(rr + j) * N + cc] = acc[mf][nf][j] + bv;
    }
  }
}

// ---------------------------------------------------------------------------
// Per-row RMSNorm + RoPE from bf16 qk rows -> head-major q/k [NH][S][HD].
// q scaled by 0.125*log2(e) (softmax in exp2 space).
// ---------------------------------------------------------------------------
__global__ __launch_bounds__(256) void norm_rope(const unsigned short* __restrict__ qk,
                                                 const float* __restrict__ qw,
                                                 const float* __restrict__ kw,
                                                 const float* __restrict__ fr,
                                                 unsigned short* __restrict__ qo,
                                                 unsigned short* __restrict__ ko) {
  __shared__ float buf[1024];
  __shared__ float red[4];
  const int s = blockIdx.x, t = threadIdx.x;
  const int lane = t & 63, w = t >> 6;
  const int e = t * 4;
  const int hh = e >> 6, dd = e & 63;
  const float* frow = fr + (size_t)s * 32;
  float cs[4], sn[4];
#pragma unroll
  for (int i = 0; i < 4; ++i) {
    float f = frow[(dd + i) & 31];
    cs[i] = cosf(f);
    sn[i] = sinf(f);
  }
  for (int part = 0; part < 2; ++part) {
    const unsigned short* row = qk + (size_t)s * 2048 + part * 1024;
    const float* wvp = part ? kw : qw;
    unsigned short* op = part ? ko : qo;
    const float oscale = part ? 1.0f : 0.18033688011112042f;
    ushort4 uv = *(const ushort4*)(row + e);
    float vx = bf2f(uv.x), vy = bf2f(uv.y), vz = bf2f(uv.z), vw = bf2f(uv.w);
    float ssq = vx * vx + vy * vy + vz * vz + vw * vw;
#pragma unroll
    for (int off = 1; off < 64; off <<= 1) ssq += __shfl_xor(ssq, off, 64);
    if (part) __syncthreads();
    if (lane == 0) red[w] = ssq;
    __syncthreads();
    float inv = rsqrtf((red[0] + red[1] + red[2] + red[3]) * (1.0f / 1024.0f) + 1e-6f);
    float4 wv = *(const float4*)(wvp + e);
    buf[e + 0] = vx * inv * wv.x;
    buf[e + 1] = vy * inv * wv.y;
    buf[e + 2] = vz * inv * wv.z;
    buf[e + 3] = vw * inv * wv.w;
    __syncthreads();
    unsigned short ov[4];
#pragma unroll
    for (int i = 0; i < 4; ++i) {
      int di = dd + i;
      float x = buf[e + i];
      float rot = (di < 32) ? -buf[e + i + 32] : buf[e + i - 32];
      ov[i] = f2bf((x * cs[i] + rot * sn[i]) * oscale);
    }
    unsigned short* dst = op + (size_t)hh * S * HD + (size_t)s * HD + dd;
    dst[0] = ov[0]; dst[1] = ov[1]; dst[2] = ov[2]; dst[3] = ov[3];
  }
}

// ---------------------------------------------------------------------------
// QK^T (32x32): S^T[kv 64][q 32] += K . Q^T from swizzled [64][64] K LDS tile.
// ---------------------------------------------------------------------------
__device__ __forceinline__ void qk_tile32(f32x16& s0, f32x16& s1,
                                          const unsigned short* Kbuf,
                                          const bf16x8* qB, int l31, int l5) {
  const int x7 = l31 & 7;
#pragma unroll
  for (int c = 0; c < 4; ++c) {
    const int ch = (2 * c + l5) ^ x7;
    bf16x8 ka0 = *(const bf16x8*)&Kbuf[l31 * 64 + ch * 8];
    bf16x8 ka1 = *(const bf16x8*)&Kbuf[(32 + l31) * 64 + ch * 8];
    s0 = MFMA32(ka0, qB[c], s0);
    s1 = MFMA32(ka1, qB[c], s1);
  }
}

// ---------------------------------------------------------------------------
// Flash attention, 32x32 MFMA, 4 waves x 32 q-rows (block = 128 q-rows).
// Swapped QK^T; in-register softmax (defer-max with __all gate); P->B-frags
// via cvt_pk + permlane32_swap. 2-deep QK pipeline, K dbuf + V 3-ring.
// grid: 512 = XCD-grouped (h,seg) x 8 q-tiles of 128.  [round-14 version]
// ---------------------------------------------------------------------------
__global__ __launch_bounds__(256) void attn_kernel(const unsigned short* __restrict__ q,
                                                   const unsigned short* __restrict__ k,
                                                   const unsigned short* __restrict__ vt,
                                                   unsigned short* __restrict__ aout) {
  __shared__ __align__(16) unsigned short Ks[2][4096];
  __shared__ __align__(16) unsigned short Vs[3][4096];
  const int bid = blockIdx.x;
  const int xcd = bid & 7;
  const int idx = bid >> 3;
  const int gw = idx >> 3, qt = idx & 7;
  const int g = xcd * 8 + gw;
  const int h = g >> 2, seg = g & 3;
  const int t = threadIdx.x, lane = t & 63, w = t >> 6;
  const int l31 = lane & 31, l5 = lane >> 5;
  const size_t hb = (size_t)h * S * HD;
  const int q0 = seg * 1024 + qt * 128 + w * 32;
  const int kvbase = seg * 1024;

  const int sr = t >> 3;               // tile row 0..31
  const int scb = (t & 7) ^ (sr & 7);  // swizzled source column-chunk
  const unsigned short* ksrcA = k + hb + (size_t)(kvbase + sr) * HD + scb * 8;
  const unsigned short* ksrcB = ksrcA + 32 * HD;
  const unsigned short* vsrcA = vt + (size_t)h * HD * S + (size_t)sr * S + kvbase + scb * 8;
  const unsigned short* vsrcB = vsrcA + (size_t)32 * S;

  // Q B-frags: 4 d-chunks of 16
  const unsigned short* qp = q + hb + (size_t)(q0 + l31) * HD + l5 * 8;
  bf16x8 qB[4];
#pragma unroll
  for (int c = 0; c < 4; ++c) qB[c] = *(const bf16x8*)(qp + 16 * c);

  f32x16 o0 = {}, o1 = {};
  float m = -1e30f, l = 0.f;

  // prologue: stage K0,K1,V0,V1
  gld_lds16(ksrcA, &Ks[0][w * 512]);
  gld_lds16(ksrcB, &Ks[0][2048 + w * 512]);
  gld_lds16(ksrcA + 4096, &Ks[1][w * 512]);
  gld_lds16(ksrcB + 4096, &Ks[1][2048 + w * 512]);
  gld_lds16(vsrcA, &Vs[0][w * 512]);
  gld_lds16(vsrcB, &Vs[0][2048 + w * 512]);
  gld_lds16(vsrcA + 64, &Vs[1][w * 512]);
  gld_lds16(vsrcB + 64, &Vs[1][2048 + w * 512]);
  __syncthreads();

  f32x16 cur0 = {}, cur1 = {};
  qk_tile32(cur0, cur1, Ks[0], qB, l31, l5);
  __syncthreads();  // tile-0 K reads retired before iter0 overwrites Ks[0]

#pragma unroll
  for (int it = 0; it < 16; ++it) {
    // stage tile it+2
    if (it < 14) {
      gld_lds16(ksrcA + (it + 2) * 4096, &Ks[it & 1][w * 512]);
      gld_lds16(ksrcB + (it + 2) * 4096, &Ks[it & 1][2048 + w * 512]);
      gld_lds16(vsrcA + (it + 2) * 64, &Vs[(it + 2) % 3][w * 512]);
      gld_lds16(vsrcB + (it + 2) * 64, &Vs[(it + 2) % 3][2048 + w * 512]);
    }
    // issue QK MFMAs for tile it+1 (consumed next iteration)
    f32x16 nxt0 = {}, nxt1 = {};
    if (it < 15) {
      __builtin_amdgcn_s_setprio(1);
      qk_tile32(nxt0, nxt1, Ks[(it + 1) & 1], qB, l31, l5);
      __builtin_amdgcn_s_setprio(0);
      __builtin_amdgcn_sched_barrier(0);
    }
    // ---- in-register softmax on cur (32 values/lane), exp2, defer-max ----
    float mm[16];
#pragma unroll
    for (int i = 0; i < 16; ++i) mm[i] = fmaxf(cur0[i], cur1[i]);
#pragma unroll
    for (int st = 8; st > 0; st >>= 1)
#pragma unroll
      for (int i = 0; i < 8; ++i)
        if (i < st) mm[i] = fmaxf(mm[i], mm[i + st]);
    float lmax = fmaxf(mm[0], __shfl_xor(mm[0], 32, 64));
    if (!__all(lmax <= m + 8.0f)) {  // rescale (always on it==0)
      const float mn = fmaxf(m, lmax);
      const float corr = exp2f(m - mn);
      m = mn;
      l *= corr;
#pragma unroll
      for (int i = 0; i < 16; ++i) { o0[i] *= corr; o1[i] *= corr; }
    }
    // P = exp2(S - m), pack to bf16 pairs (reg pairs are adjacent kv)
    unsigned pk0[8], pk1[8];
    float ls0 = 0.f, ls1 = 0.f;
#pragma unroll
    for (int i = 0; i < 8; ++i) {
      float a0 = exp2f(cur0[2 * i] - m), a1 = exp2f(cur0[2 * i + 1] - m);
      float b0 = exp2f(cur1[2 * i] - m), b1 = exp2f(cur1[2 * i + 1] - m);
      ls0 += a0 + a1;
      ls1 += b0 + b1;
      pk0[i] = cvtpk(a0, a1);
      pk1[i] = cvtpk(b0, b1);
    }
    l += ls0 + ls1;
    // ---- build PV B-frags: per kv-chunk c: 2 permlane32_swap ----
    bf16x8 pB[4];
#pragma unroll
    for (int c = 0; c < 4; ++c) {
      const int cl = c & 1;
      unsigned w0, w1, w2, w3;
      if (c < 2) { w0 = pk0[4 * cl + 0]; w1 = pk0[4 * cl + 1]; w2 = pk0[4 * cl + 2]; w3 = pk0[4 * cl + 3]; }
      else       { w0 = pk1[4 * cl + 0]; w1 = pk1[4 * cl + 1]; w2 = pk1[4 * cl + 2]; w3 = pk1[4 * cl + 3]; }
      pl32swap(w0, w2);
      pl32swap(w1, w3);
      uint4 bw;
      bw.x = w0; bw.y = w1; bw.z = w2; bw.w = w3;
      pB[c] = __builtin_bit_cast(bf16x8, bw);
    }
    // ---- O^T += V^T . P^T : A-frags from swizzled V tile ----
    const unsigned short* Vbuf = Vs[it % 3];
    const int x7 = l31 & 7;
    __builtin_amdgcn_s_setprio(1);
#pragma unroll
    for (int c = 0; c < 4; ++c) {
      const int ch = (2 * c + l5) ^ x7;
      bf16x8 va0 = *(const bf16x8*)&Vbuf[l31 * 64 + ch * 8];
      bf16x8 va1 = *(const bf16x8*)&Vbuf[(32 + l31) * 64 + ch * 8];
      o0 = MFMA32(va0, pB[c], o0);
      o1 = MFMA32(va1, pB[c], o1);
    }
    __builtin_amdgcn_s_setprio(0);
    __syncthreads();
    cur0 = nxt0;
    cur1 = nxt1;
  }

  // final l reduce across the 32-half pair, then epilogue
  l += __shfl_xor(l, 32, 64);
  const float invl = 1.0f / l;
#pragma unroll
  for (int blk = 0; blk < 2; ++blk) {
#pragma unroll
    for (int rg = 0; rg < 4; ++rg) {
      const f32x16& o = blk ? o1 : o0;
      ushort4 u;
      u.x = f2bf(o[4 * rg + 0] * invl);
      u.y = f2bf(o[4 * rg + 1] * invl);
      u.z = f2bf(o[4 * rg + 2] * invl);
      u.w = f2bf(o[4 * rg + 3] * invl);
      const int dcol = 32 * blk + 8 * rg + 4 * l5;
      *(ushort4*)(aout + (size_t)(q0 + l31) * D + h * 64 + dcol) = u;
    }
  }
}

// ---------------------------------------------------------------------------
extern "C" void kernel_launch(void* const* d_in, const int* in_sizes, int n_in,
                              void* d_out, int out_size, void* d_ws, size_t ws_size,
                              hipStream_t stream) {
  const float* hidden = (const float*)d_in[0];
  const float* qkvw   = (const float*)d_in[1];
  const float* qkvb   = (const float*)d_in[2];
  const float* projw  = (const float*)d_in[3];
  const float* projb  = (const float*)d_in[4];
  const float* qnw    = (const float*)d_in[5];
  const float* knw    = (const float*)d_in[6];
  const float* freqs  = (const float*)d_in[7];
  float* out = (float*)d_out;
  char* ws = (char*)d_ws;

  unsigned short* hb  = (unsigned short*)(ws + 0);               // 8 MB  hidden bf16
  unsigned short* wb  = (unsigned short*)(ws + (8u << 20));      // 6 MB  qkv_w bf16
  unsigned short* pb  = (unsigned short*)(ws + (14u << 20));     // 2 MB  proj_w bf16
  unsigned short* qk  = (unsigned short*)(ws + (16u << 20));     // 16 MB q|k bf16 [4096][2048]
  unsigned short* vtb = (unsigned short*)(ws + (32u << 20));     // 8 MB  v^T bf16 [16][64][4096]
  unsigned short* qb  = (unsigned short*)(ws + (40u << 20));     // 8 MB  q bf16 [16][4096][64]
  unsigned short* kb  = (unsigned short*)(ws + (48u << 20));     // 8 MB  k bf16 [16][4096][64]
  unsigned short* ab  = (unsigned short*)(ws + (56u << 20));     // 8 MB  attn bf16 [4096][1024]

  cvt3<<<8192, 256, 0, stream>>>(hidden, hb, qkvw, wb, projw, pb);
  gemm_qkv<<<dim3(24, 32), 256, 0, stream>>>(hb, wb, qkvb, qk, vtb);
  norm_rope<<<4096, 256, 0, stream>>>(qk, qnw, knw, freqs, qb, kb);
  attn_kernel<<<512, 256, 0, stream>>>(qb, kb, vtb, ab);
  gemm_bt<<<dim3(8, 32), 256, 0, stream>>>(ab, pb, projb, out, 4096, 1024, 1024, 8);
}

// Round 20
// 112.760 us; speedup vs baseline: 1.1111x; 1.0199x over previous
//
#include <hip/hip_runtime.h>
#include <hip/hip_bf16.h>

#define S 4096
#define D 1024
#define NH 16
#define HD 64

typedef float f32x4 __attribute__((ext_vector_type(4)));
typedef float f32x16 __attribute__((ext_vector_type(16)));
typedef __bf16 bf16x8 __attribute__((ext_vector_type(8)));

#define MFMA16(a, b, c) __builtin_amdgcn_mfma_f32_16x16x32_bf16((a), (b), (c), 0, 0, 0)
#define MFMA32(a, b, c) __builtin_amdgcn_mfma_f32_32x32x16_bf16((a), (b), (c), 0, 0, 0)

__device__ __forceinline__ unsigned short f2bf(float f) {
  unsigned int u = __builtin_bit_cast(unsigned int, f);
  u += 0x7FFFu + ((u >> 16) & 1u);
  return (unsigned short)(u >> 16);
}

__device__ __forceinline__ float bf2f(unsigned short u) {
  unsigned int x = ((unsigned int)u) << 16;
  return __builtin_bit_cast(float, x);
}

__device__ __forceinline__ unsigned cvtpk(float lo, float hi) {
  unsigned r;
  asm("v_cvt_pk_bf16_f32 %0, %1, %2" : "=v"(r) : "v"(lo), "v"(hi));
  return r;
}

// exchange: a.hi-lanes <-> b.lo-lanes (a'[i>=32]=b[i-32], b'[i<32]=a[i+32])
__device__ __forceinline__ void pl32swap(unsigned& a, unsigned& b) {
#if __has_builtin(__builtin_amdgcn_permlane32_swap)
  typedef unsigned u32x2 __attribute__((ext_vector_type(2)));
  u32x2 r = __builtin_amdgcn_permlane32_swap(a, b, false, false);
  a = r.x;
  b = r.y;
#else
  asm volatile("v_permlane32_swap_b32 %0, %1" : "+v"(a), "+v"(b));
#endif
}

typedef __attribute__((address_space(1))) void GAS;
typedef __attribute__((address_space(3))) void LAS;

__device__ __forceinline__ void gld_lds16(const unsigned short* g, unsigned short* l) {
  __builtin_amdgcn_global_load_lds((GAS*)g, (LAS*)l, 16, 0, 0);
}

// ---------------------------------------------------------------------------
// fused f32 -> bf16 convert of hidden (1048576 f4), qkv_w (786432 f4),
// proj_w (262144 f4) in one launch. 8192 blocks x 256 threads.
// ---------------------------------------------------------------------------
__global__ void cvt3(const float* __restrict__ a, unsigned short* __restrict__ ao,
                     const float* __restrict__ b, unsigned short* __restrict__ bo,
                     const float* __restrict__ c, unsigned short* __restrict__ co) {
  int i = blockIdx.x * blockDim.x + threadIdx.x;
  const float* in;
  unsigned short* out;
  int j;
  if (i < 1048576) { in = a; out = ao; j = i; }
  else if (i < 1835008) { in = b; out = bo; j = i - 1048576; }
  else { in = c; out = co; j = i - 1835008; }
  float4 v = ((const float4*)in)[j];
  ushort4 u;
  u.x = f2bf(v.x); u.y = f2bf(v.y); u.z = f2bf(v.z); u.w = f2bf(v.w);
  ((ushort4*)out)[j] = u;
}

// bijective XCD swizzle of a linear block id (nwg % 8 == 0)
__device__ __forceinline__ int xcd_swz(int bid, int nwg) {
  int q = nwg >> 3;
  return (bid & 7) * q + (bid >> 3);
}

// --- Deep-pipelined K-step macros (K=1024, BK=32, 3 static buffer pairs) ----
// LDS tiles are chunk-XOR swizzled (bank-conflict fix, 8-way -> 4-way):
// LDS[r][c] holds X[r][c ^ (r&3)]; staging pre-swizzles the GLOBAL source
// chunk (o0==o1== ((t&3)^((t>>2)&3))*8, LDS dest stays linear for
// global_load_lds); reads use csw = (l4 ^ (l15&3))*8 (row&3 == l15&3).
#define DSTEP_S(RA, RB, SA, SB, KN, VM)                                          \
  {                                                                              \
    bf16x8 af[4], bfv[4];                                                        \
    _Pragma("unroll") for (int mf = 0; mf < 4; ++mf)                             \
        af[mf] = *(const bf16x8*)&RA[(wr * 64 + mf * 16 + l15) * 32 + csw];      \
    _Pragma("unroll") for (int nf = 0; nf < 4; ++nf)                             \
        bfv[nf] = *(const bf16x8*)&RB[(wc * 64 + nf * 16 + l15) * 32 + csw];     \
    gld_lds16(Ab + (size_t)r0 * 1024 + (KN) + o0, &SA[w * 512]);                 \
    gld_lds16(Ab + (size_t)r1 * 1024 + (KN) + o1, &SA[2048 + w * 512]);          \
    gld_lds16(Bb + (size_t)r0 * 1024 + (KN) + o0, &SB[w * 512]);                 \
    gld_lds16(Bb + (size_t)r1 * 1024 + (KN) + o1, &SB[2048 + w * 512]);          \
    _Pragma("unroll") for (int mf = 0; mf < 4; ++mf)                             \
        _Pragma("unroll") for (int nf = 0; nf < 4; ++nf)                         \
            acc[mf][nf] = MFMA16(af[mf], bfv[nf], acc[mf][nf]);                  \
    asm volatile("s_waitcnt vmcnt(" VM ")" ::: "memory");                        \
    __builtin_amdgcn_s_barrier();                                                \
  }

#define DSTEP_N(RA, RB, VM)                                                      \
  {                                                                              \
    bf16x8 af[4], bfv[4];                                                        \
    _Pragma("unroll") for (int mf = 0; mf < 4; ++mf)                             \
        af[mf] = *(const bf16x8*)&RA[(wr * 64 + mf * 16 + l15) * 32 + csw];      \
    _Pragma("unroll") for (int nf = 0; nf < 4; ++nf)                             \
        bfv[nf] = *(const bf16x8*)&RB[(wc * 64 + nf * 16 + l15) * 32 + csw];     \
    _Pragma("unroll") for (int mf = 0; mf < 4; ++mf)                             \
        _Pragma("unroll") for (int nf = 0; nf < 4; ++nf)                         \
            acc[mf][nf] = MFMA16(af[mf], bfv[nf], acc[mf][nf]);                  \
    asm volatile("s_waitcnt vmcnt(" VM ")" ::: "memory");                        \
    __builtin_amdgcn_s_barrier();                                                \
  }

#define DSTEP_LAST(RA, RB)                                                       \
  {                                                                              \
    bf16x8 af[4], bfv[4];                                                        \
    _Pragma("unroll") for (int mf = 0; mf < 4; ++mf)                             \
        af[mf] = *(const bf16x8*)&RA[(wr * 64 + mf * 16 + l15) * 32 + csw];      \
    _Pragma("unroll") for (int nf = 0; nf < 4; ++nf)                             \
        bfv[nf] = *(const bf16x8*)&RB[(wc * 64 + nf * 16 + l15) * 32 + csw];     \
    _Pragma("unroll") for (int mf = 0; mf < 4; ++mf)                             \
        _Pragma("unroll") for (int nf = 0; nf < 4; ++nf)                         \
            acc[mf][nf] = MFMA16(af[mf], bfv[nf], acc[mf][nf]);                  \
  }

#define GEMM_PRO_LOOP()                                                          \
  gld_lds16(Ab + (size_t)r0 * 1024 + o0, &As0[w * 512]);                         \
  gld_lds16(Ab + (size_t)r1 * 1024 + o1, &As0[2048 + w * 512]);                  \
  gld_lds16(Bb + (size_t)r0 * 1024 + o0, &Bs0[w * 512]);                         \
  gld_lds16(Bb + (size_t)r1 * 1024 + o1, &Bs0[2048 + w * 512]);                  \
  gld_lds16(Ab + (size_t)r0 * 1024 + 32 + o0, &As1[w * 512]);                    \
  gld_lds16(Ab + (size_t)r1 * 1024 + 32 + o1, &As1[2048 + w * 512]);             \
  gld_lds16(Bb + (size_t)r0 * 1024 + 32 + o0, &Bs1[w * 512]);                    \
  gld_lds16(Bb + (size_t)r1 * 1024 + 32 + o1, &Bs1[2048 + w * 512]);             \
  asm volatile("s_waitcnt vmcnt(4)" ::: "memory");                               \
  __builtin_amdgcn_s_barrier();                                                  \
  _Pragma("unroll 1") for (int k0 = 0; k0 < 960; k0 += 96) {                     \
    DSTEP_S(As0, Bs0, As2, Bs2, k0 + 64, "4")                                    \
    DSTEP_S(As1, Bs1, As0, Bs0, k0 + 96, "4")                                    \
    DSTEP_S(As2, Bs2, As1, Bs1, k0 + 128, "4")                                   \
  }                                                                              \
  DSTEP_N(As0, Bs0, "0")                                                         \
  DSTEP_LAST(As1, Bs1)

// ---------------------------------------------------------------------------
// QKV GEMM: qkv[4096 x 3072] = hidden @ qkv_w^T + b. L2-partitioned per XCD.
// 3-deep counted-vmcnt pipelined K-loop, launch_bounds(256,3) -> 3 blocks/CU.
// LDS chunk-XOR swizzle on staging/read (bank-conflict 8-way -> 4-way).
// ---------------------------------------------------------------------------
__global__ __launch_bounds__(256, 3) void gemm_qkv(const unsigned short* __restrict__ A,
                                                   const unsigned short* __restrict__ B,
                                                   const float* __restrict__ bias,
                                                   unsigned short* __restrict__ qk,
                                                   unsigned short* __restrict__ vt) {
  __shared__ __align__(16) unsigned short As0[4096], As1[4096], As2[4096];
  __shared__ __align__(16) unsigned short Bs0[4096], Bs1[4096], Bs2[4096];
  __shared__ __align__(16) unsigned short tr[128 * 17];  // 16-col transpose chunk
  const int t = threadIdx.x;
  const int lane = t & 63;
  const int w = t >> 6;
  const int wr = w >> 1, wc = w & 1;
  const int l15 = lane & 15, l4 = lane >> 4;
  const int bid = blockIdx.y * 24 + blockIdx.x;
  const int r8 = bid & 7, i = bid >> 3;
  const int by = (r8 >> 1) * 8 + i / 12;
  const int bx = (r8 & 1) * 12 + i % 12;
  const int m0 = by * 128, n0 = bx * 128;

  f32x4 acc[4][4] = {};

  const int r0 = t >> 2;
  const int r1 = 64 + (t >> 2);
  const int o0 = (((t & 3) ^ ((t >> 2) & 3))) * 8;  // pre-swizzled source chunk
  const int o1 = o0;                                // (256+t)&3 == t&3, same row&3
  const int csw = (l4 ^ (l15 & 3)) * 8;             // swizzled read chunk
  const unsigned short* Ab = A + (size_t)m0 * 1024;
  const unsigned short* Bb = B + (size_t)n0 * 1024;

  GEMM_PRO_LOOP()

  if (n0 < 2048) {
#pragma unroll
    for (int mf = 0; mf < 4; ++mf)
#pragma unroll
      for (int nf = 0; nf < 4; ++nf) {
        int rr = m0 + wr * 64 + mf * 16 + l4 * 4;
        int cc = n0 + wc * 64 + nf * 16 + l15;
        float bv = bias[cc];
#pragma unroll
        for (int j = 0; j < 4; ++j)
          qk[(size_t)(rr + j) * 2048 + cc] = f2bf(acc[mf][nf][j] + bv);
      }
  } else {
    const int h0 = (n0 - 2048) >> 6;
#pragma unroll
    for (int ch = 0; ch < 8; ++ch) {
      __syncthreads();
      if (wc == (ch >> 2)) {
        const int nf = ch & 3;
        const float bv = bias[n0 + (ch >> 2) * 64 + nf * 16 + l15];
#pragma unroll
        for (int mf = 0; mf < 4; ++mf) {
          int srow = wr * 64 + mf * 16 + l4 * 4;
#pragma unroll
          for (int j = 0; j < 4; ++j)
            tr[(srow + j) * 17 + l15] = f2bf(acc[mf][nf][j] + bv);
        }
      }
      __syncthreads();
      const int hh = h0 + (ch >> 2);
      const int dbase = (ch & 3) * 16;
#pragma unroll
      for (int i2 = 0; i2 < 2; ++i2) {
        int g = i2 * 256 + t;
        int dp = g >> 5, sg = g & 31;
        ushort4 u;
        u.x = tr[(sg * 4 + 0) * 17 + dp];
        u.y = tr[(sg * 4 + 1) * 17 + dp];
        u.z = tr[(sg * 4 + 2) * 17 + dp];
        u.w = tr[(sg * 4 + 3) * 17 + dp];
        *(ushort4*)(vt + (size_t)hh * HD * S + (size_t)(dbase + dp) * S + m0 + sg * 4) = u;
      }
    }
  }
}

// ---------------------------------------------------------------------------
// proj GEMM: out f32 = A bf16 @ B^T bf16 + bias. Same pipelined K-loop +
// LDS chunk-XOR swizzle.
// ---------------------------------------------------------------------------
__global__ __launch_bounds__(256, 3) void gemm_bt(const unsigned short* __restrict__ A,
                                                  const unsigned short* __restrict__ B,
                                                  const float* __restrict__ bias,
                                                  float* __restrict__ C,
                                                  int M, int N, int K, int gx) {
  __shared__ __align__(16) unsigned short As0[4096], As1[4096], As2[4096];
  __shared__ __align__(16) unsigned short Bs0[4096], Bs1[4096], Bs2[4096];
  const int t = threadIdx.x;
  const int lane = t & 63;
  const int w = t >> 6;
  const int wr = w >> 1, wc = w & 1;
  const int l15 = lane & 15, l4 = lane >> 4;
  const int nwg = gridDim.x * gridDim.y;
  const int nbid = xcd_swz(blockIdx.y * gx + blockIdx.x, nwg);
  const int m0 = (nbid / gx) * 128, n0 = (nbid % gx) * 128;

  f32x4 acc[4][4] = {};

  const int r0 = t >> 2;
  const int r1 = 64 + (t >> 2);
  const int o0 = (((t & 3) ^ ((t >> 2) & 3))) * 8;
  const int o1 = o0;
  const int csw = (l4 ^ (l15 & 3)) * 8;
  const unsigned short* Ab = A + (size_t)m0 * 1024;
  const unsigned short* Bb = B + (size_t)n0 * 1024;

  GEMM_PRO_LOOP()

#pragma unroll
  for (int mf = 0; mf < 4; ++mf) {
#pragma unroll
    for (int nf = 0; nf < 4; ++nf) {
      int rr = m0 + wr * 64 + mf * 16 + l4 * 4;
      int cc = n0 + wc * 64 + nf * 16 + l15;
      float bv = bias[cc];
#pragma unroll
      for (int j = 0; j < 4; ++j)
        C[(size_t)(rr + j) * N + cc] = acc[mf][nf][j] + bv;
    }
  }
}

// ---------------------------------------------------------------------------
// Per-row RMSNorm + RoPE from bf16 qk rows -> head-major q/k [NH][S][HD].
// q scaled by 0.125*log2(e). Trig of the 32 unique freqs computed ONCE per
// block into LDS (was 2048 redundant cosf/sinf per block).
// ---------------------------------------------------------------------------
__global__ __launch_bounds__(256) void norm_rope(const unsigned short* __restrict__ qk,
                                                 const float* __restrict__ qw,
                                                 const float* __restrict__ kw,
                                                 const float* __restrict__ fr,
                                                 unsigned short* __restrict__ qo,
                                                 unsigned short* __restrict__ ko) {
  __shared__ float buf[1024];
  __shared__ float red[4];
  __shared__ float scs[32], ssn[32];
  const int s = blockIdx.x, t = threadIdx.x;
  const int lane = t & 63, w = t >> 6;
  const int e = t * 4;
  const int hh = e >> 6, dd = e & 63;
  const float* frow = fr + (size_t)s * 32;
  if (t < 32) {
    float f = frow[t];
    scs[t] = cosf(f);
    ssn[t] = sinf(f);
  }
  __syncthreads();
  float cs[4], sn[4];
#pragma unroll
  for (int i = 0; i < 4; ++i) {
    int fi = (dd + i) & 31;
    cs[i] = scs[fi];
    sn[i] = ssn[fi];
  }
  for (int part = 0; part < 2; ++part) {
    const unsigned short* row = qk + (size_t)s * 2048 + part * 1024;
    const float* wvp = part ? kw : qw;
    unsigned short* op = part ? ko : qo;
    const float oscale = part ? 1.0f : 0.18033688011112042f;
    ushort4 uv = *(const ushort4*)(row + e);
    float vx = bf2f(uv.x), vy = bf2f(uv.y), vz = bf2f(uv.z), vw = bf2f(uv.w);
    float ssq = vx * vx + vy * vy + vz * vz + vw * vw;
#pragma unroll
    for (int off = 1; off < 64; off <<= 1) ssq += __shfl_xor(ssq, off, 64);
    if (part) __syncthreads();
    if (lane == 0) red[w] = ssq;
    __syncthreads();
    float inv = rsqrtf((red[0] + red[1] + red[2] + red[3]) * (1.0f / 1024.0f) + 1e-6f);
    float4 wv = *(const float4*)(wvp + e);
    buf[e + 0] = vx * inv * wv.x;
    buf[e + 1] = vy * inv * wv.y;
    buf[e + 2] = vz * inv * wv.z;
    buf[e + 3] = vw * inv * wv.w;
    __syncthreads();
    unsigned short ov[4];
#pragma unroll
    for (int i = 0; i < 4; ++i) {
      int di = dd + i;
      float x = buf[e + i];
      float rot = (di < 32) ? -buf[e + i + 32] : buf[e + i - 32];
      ov[i] = f2bf((x * cs[i] + rot * sn[i]) * oscale);
    }
    unsigned short* dst = op + (size_t)hh * S * HD + (size_t)s * HD + dd;
    dst[0] = ov[0]; dst[1] = ov[1]; dst[2] = ov[2]; dst[3] = ov[3];
  }
}

// ---------------------------------------------------------------------------
// QK^T (32x32): S^T[kv 64][q 32] += K . Q^T from swizzled [64][64] K LDS tile.
// ---------------------------------------------------------------------------
__device__ __forceinline__ void qk_tile32(f32x16& s0, f32x16& s1,
                                          const unsigned short* Kbuf,
                                          const bf16x8* qB, int l31, int l5) {
  const int x7 = l31 & 7;
#pragma unroll
  for (int c = 0; c < 4; ++c) {
    const int ch = (2 * c + l5) ^ x7;
    bf16x8 ka0 = *(const bf16x8*)&Kbuf[l31 * 64 + ch * 8];
    bf16x8 ka1 = *(const bf16x8*)&Kbuf[(32 + l31) * 64 + ch * 8];
    s0 = MFMA32(ka0, qB[c], s0);
    s1 = MFMA32(ka1, qB[c], s1);
  }
}

// ---------------------------------------------------------------------------
// Flash attention, 32x32 MFMA, 4 waves x 32 q-rows (block = 128 q-rows).
// Swapped QK^T; in-register softmax (defer-max with __all gate); P->B-frags
// via cvt_pk + permlane32_swap. 2-deep QK pipeline, K dbuf + V 3-ring.
// grid: 512 = XCD-grouped (h,seg) x 8 q-tiles of 128.  [round-14 version]
// ---------------------------------------------------------------------------
__global__ __launch_bounds__(256) void attn_kernel(const unsigned short* __restrict__ q,
                                                   const unsigned short* __restrict__ k,
                                                   const unsigned short* __restrict__ vt,
                                                   unsigned short* __restrict__ aout) {
  __shared__ __align__(16) unsigned short Ks[2][4096];
  __shared__ __align__(16) unsigned short Vs[3][4096];
  const int bid = blockIdx.x;
  const int xcd = bid & 7;
  const int idx = bid >> 3;
  const int gw = idx >> 3, qt = idx & 7;
  const int g = xcd * 8 + gw;
  const int h = g >> 2, seg = g & 3;
  const int t = threadIdx.x, lane = t & 63, w = t >> 6;
  const int l31 = lane & 31, l5 = lane >> 5;
  const size_t hb = (size_t)h * S * HD;
  const int q0 = seg * 1024 + qt * 128 + w * 32;
  const int kvbase = seg * 1024;

  const int sr = t >> 3;               // tile row 0..31
  const int scb = (t & 7) ^ (sr & 7);  // swizzled source column-chunk
  const unsigned short* ksrcA = k + hb + (size_t)(kvbase + sr) * HD + scb * 8;
  const unsigned short* ksrcB = ksrcA + 32 * HD;
  const unsigned short* vsrcA = vt + (size_t)h * HD * S + (size_t)sr * S + kvbase + scb * 8;
  const unsigned short* vsrcB = vsrcA + (size_t)32 * S;

  // Q B-frags: 4 d-chunks of 16
  const unsigned short* qp = q + hb + (size_t)(q0 + l31) * HD + l5 * 8;
  bf16x8 qB[4];
#pragma unroll
  for (int c = 0; c < 4; ++c) qB[c] = *(const bf16x8*)(qp + 16 * c);

  f32x16 o0 = {}, o1 = {};
  float m = -1e30f, l = 0.f;

  // prologue: stage K0,K1,V0,V1
  gld_lds16(ksrcA, &Ks[0][w * 512]);
  gld_lds16(ksrcB, &Ks[0][2048 + w * 512]);
  gld_lds16(ksrcA + 4096, &Ks[1][w * 512]);
  gld_lds16(ksrcB + 4096, &Ks[1][2048 + w * 512]);
  gld_lds16(vsrcA, &Vs[0][w * 512]);
  gld_lds16(vsrcB, &Vs[0][2048 + w * 512]);
  gld_lds16(vsrcA + 64, &Vs[1][w * 512]);
  gld_lds16(vsrcB + 64, &Vs[1][2048 + w * 512]);
  __syncthreads();

  f32x16 cur0 = {}, cur1 = {};
  qk_tile32(cur0, cur1, Ks[0], qB, l31, l5);
  __syncthreads();  // tile-0 K reads retired before iter0 overwrites Ks[0]

#pragma unroll
  for (int it = 0; it < 16; ++it) {
    // stage tile it+2
    if (it < 14) {
      gld_lds16(ksrcA + (it + 2) * 4096, &Ks[it & 1][w * 512]);
      gld_lds16(ksrcB + (it + 2) * 4096, &Ks[it & 1][2048 + w * 512]);
      gld_lds16(vsrcA + (it + 2) * 64, &Vs[(it + 2) % 3][w * 512]);
      gld_lds16(vsrcB + (it + 2) * 64, &Vs[(it + 2) % 3][2048 + w * 512]);
    }
    // issue QK MFMAs for tile it+1 (consumed next iteration)
    f32x16 nxt0 = {}, nxt1 = {};
    if (it < 15) {
      __builtin_amdgcn_s_setprio(1);
      qk_tile32(nxt0, nxt1, Ks[(it + 1) & 1], qB, l31, l5);
      __builtin_amdgcn_s_setprio(0);
      __builtin_amdgcn_sched_barrier(0);
    }
    // ---- in-register softmax on cur (32 values/lane), exp2, defer-max ----
    float mm[16];
#pragma unroll
    for (int i = 0; i < 16; ++i) mm[i] = fmaxf(cur0[i], cur1[i]);
#pragma unroll
    for (int st = 8; st > 0; st >>= 1)
#pragma unroll
      for (int i = 0; i < 8; ++i)
        if (i < st) mm[i] = fmaxf(mm[i], mm[i + st]);
    float lmax = fmaxf(mm[0], __shfl_xor(mm[0], 32, 64));
    if (!__all(lmax <= m + 8.0f)) {  // rescale (always on it==0)
      const float mn = fmaxf(m, lmax);
      const float corr = exp2f(m - mn);
      m = mn;
      l *= corr;
#pragma unroll
      for (int i = 0; i < 16; ++i) { o0[i] *= corr; o1[i] *= corr; }
    }
    // P = exp2(S - m), pack to bf16 pairs (reg pairs are adjacent kv)
    unsigned pk0[8], pk1[8];
    float ls0 = 0.f, ls1 = 0.f;
#pragma unroll
    for (int i = 0; i < 8; ++i) {
      float a0 = exp2f(cur0[2 * i] - m), a1 = exp2f(cur0[2 * i + 1] - m);
      float b0 = exp2f(cur1[2 * i] - m), b1 = exp2f(cur1[2 * i + 1] - m);
      ls0 += a0 + a1;
      ls1 += b0 + b1;
      pk0[i] = cvtpk(a0, a1);
      pk1[i] = cvtpk(b0, b1);
    }
    l += ls0 + ls1;
    // ---- build PV B-frags: per kv-chunk c: 2 permlane32_swap ----
    bf16x8 pB[4];
#pragma unroll
    for (int c = 0; c < 4; ++c) {
      const int cl = c & 1;
      unsigned w0, w1, w2, w3;
      if (c < 2) { w0 = pk0[4 * cl + 0]; w1 = pk0[4 * cl + 1]; w2 = pk0[4 * cl + 2]; w3 = pk0[4 * cl + 3]; }
      else       { w0 = pk1[4 * cl + 0]; w1 = pk1[4 * cl + 1]; w2 = pk1[4 * cl + 2]; w3 = pk1[4 * cl + 3]; }
      pl32swap(w0, w2);
      pl32swap(w1, w3);
      uint4 bw;
      bw.x = w0; bw.y = w1; bw.z = w2; bw.w = w3;
      pB[c] = __builtin_bit_cast(bf16x8, bw);
    }
    // ---- O^T += V^T . P^T : A-frags from swizzled V tile ----
    const unsigned short* Vbuf = Vs[it % 3];
    const int x7 = l31 & 7;
    __builtin_amdgcn_s_setprio(1);
#pragma unroll
    for (int c = 0; c < 4; ++c) {
      const int ch = (2 * c + l5) ^ x7;
      bf16x8 va0 = *(const bf16x8*)&Vbuf[l31 * 64 + ch * 8];
      bf16x8 va1 = *(const bf16x8*)&Vbuf[(32 + l31) * 64 + ch * 8];
      o0 = MFMA32(va0, pB[c], o0);
      o1 = MFMA32(va1, pB[c], o1);
    }
    __builtin_amdgcn_s_setprio(0);
    __syncthreads();
    cur0 = nxt0;
    cur1 = nxt1;
  }

  // final l reduce across the 32-half pair, then epilogue
  l += __shfl_xor(l, 32, 64);
  const float invl = 1.0f / l;
#pragma unroll
  for (int blk = 0; blk < 2; ++blk) {
#pragma unroll
    for (int rg = 0; rg < 4; ++rg) {
      const f32x16& o = blk ? o1 : o0;
      ushort4 u;
      u.x = f2bf(o[4 * rg + 0] * invl);
      u.y = f2bf(o[4 * rg + 1] * invl);
      u.z = f2bf(o[4 * rg + 2] * invl);
      u.w = f2bf(o[4 * rg + 3] * invl);
      const int dcol = 32 * blk + 8 * rg + 4 * l5;
      *(ushort4*)(aout + (size_t)(q0 + l31) * D + h * 64 + dcol) = u;
    }
  }
}

// ---------------------------------------------------------------------------
extern "C" void kernel_launch(void* const* d_in, const int* in_sizes, int n_in,
                              void* d_out, int out_size, void* d_ws, size_t ws_size,
                              hipStream_t stream) {
  const float* hidden = (const float*)d_in[0];
  const float* qkvw   = (const float*)d_in[1];
  const float* qkvb   = (const float*)d_in[2];
  const float* projw  = (const float*)d_in[3];
  const float* projb  = (const float*)d_in[4];
  const float* qnw    = (const float*)d_in[5];
  const float* knw    = (const float*)d_in[6];
  const float* freqs  = (const float*)d_in[7];
  float* out = (float*)d_out;
  char* ws = (char*)d_ws;

  unsigned short* hb  = (unsigned short*)(ws + 0);               // 8 MB  hidden bf16
  unsigned short* wb  = (unsigned short*)(ws + (8u << 20));      // 6 MB  qkv_w bf16
  unsigned short* pb  = (unsigned short*)(ws + (14u << 20));     // 2 MB  proj_w bf16
  unsigned short* qk  = (unsigned short*)(ws + (16u << 20));     // 16 MB q|k bf16 [4096][2048]
  unsigned short* vtb = (unsigned short*)(ws + (32u << 20));     // 8 MB  v^T bf16 [16][64][4096]
  unsigned short* qb  = (unsigned short*)(ws + (40u << 20));     // 8 MB  q bf16 [16][4096][64]
  unsigned short* kb  = (unsigned short*)(ws + (48u << 20));     // 8 MB  k bf16 [16][4096][64]
  unsigned short* ab  = (unsigned short*)(ws + (56u << 20));     // 8 MB  attn bf16 [4096][1024]

  cvt3<<<8192, 256, 0, stream>>>(hidden, hb, qkvw, wb, projw, pb);
  gemm_qkv<<<dim3(24, 32), 256, 0, stream>>>(hb, wb, qkvb, qk, vtb);
  norm_rope<<<4096, 256, 0, stream>>>(qk, qnw, knw, freqs, qb, kb);
  attn_kernel<<<512, 256, 0, stream>>>(qb, kb, vtb, ab);
  gemm_bt<<<dim3(8, 32), 256, 0, stream>>>(ab, pb, projb, out, 4096, 1024, 1024, 8);
}